// Round 1
// baseline (652.580 us; speedup 1.0000x reference)
//
#include <hip/hip_runtime.h>
#include <hip/hip_bf16.h>

#define NN 1024
#define DH 64
#define DIM 512
#define INNER 512
#define QKV_N 1536
#define SCALE 0.125f

// ---------------- nnz per mask row ----------------
__global__ __launch_bounds__(64) void nnz_kernel(const int* __restrict__ mask,
                                                 float* __restrict__ nnzf) {
  int row = blockIdx.x;
  int lane = threadIdx.x;
  int s = 0;
  const int* mrow = mask + (size_t)row * NN;
  for (int i = lane; i < NN; i += 64) s += (mrow[i] != 0) ? 1 : 0;
  for (int off = 32; off > 0; off >>= 1) s += __shfl_down(s, off, 64);
  if (lane == 0) nnzf[row] = (float)s;
}

// ---------------- QKV GEMM: x(8192x512) @ w_qkv(512x1536), scatter to per-head q/k/v ----------------
__global__ __launch_bounds__(256) void qkv_gemm(const float* __restrict__ A,
                                                const float* __restrict__ B,
                                                float* __restrict__ qb,
                                                float* __restrict__ kb,
                                                float* __restrict__ vb) {
  __shared__ float As[16][132];   // [k][m] transposed
  __shared__ float Bs[16][128];   // [k][n]
  int t = threadIdx.x;
  int tx = t & 15, ty = t >> 4;
  int r0 = blockIdx.y * 128;
  int c0 = blockIdx.x * 128;
  float acc[8][8];
#pragma unroll
  for (int i = 0; i < 8; ++i)
#pragma unroll
    for (int j = 0; j < 8; ++j) acc[i][j] = 0.f;

  int sar = t >> 2;           // 0..63
  int sak = (t & 3) * 4;      // 0,4,8,12
  int sbk = t >> 4;           // 0..15
  int sbc = (t & 15) * 8;

  for (int kt = 0; kt < DIM; kt += 16) {
#pragma unroll
    for (int p = 0; p < 2; ++p) {
      int ar = p * 64 + sar;
      const float4 av = *(const float4*)&A[(size_t)(r0 + ar) * DIM + kt + sak];
      As[sak + 0][ar] = av.x;
      As[sak + 1][ar] = av.y;
      As[sak + 2][ar] = av.z;
      As[sak + 3][ar] = av.w;
    }
    {
      const float4 b0 = *(const float4*)&B[(size_t)(kt + sbk) * QKV_N + c0 + sbc];
      const float4 b1 = *(const float4*)&B[(size_t)(kt + sbk) * QKV_N + c0 + sbc + 4];
      *(float4*)&Bs[sbk][sbc] = b0;
      *(float4*)&Bs[sbk][sbc + 4] = b1;
    }
    __syncthreads();
#pragma unroll
    for (int kk = 0; kk < 16; ++kk) {
      float af[8], bf[8];
      *(float4*)&af[0] = *(const float4*)&As[kk][ty * 8];
      *(float4*)&af[4] = *(const float4*)&As[kk][ty * 8 + 4];
      *(float4*)&bf[0] = *(const float4*)&Bs[kk][tx * 8];
      *(float4*)&bf[4] = *(const float4*)&Bs[kk][tx * 8 + 4];
#pragma unroll
      for (int i = 0; i < 8; ++i)
#pragma unroll
        for (int j = 0; j < 8; ++j) acc[i][j] = fmaf(af[i], bf[j], acc[i][j]);
    }
    __syncthreads();
  }
  // scatter store into q/k/v [b][h][n][d]
#pragma unroll
  for (int i = 0; i < 8; ++i) {
    int r = r0 + ty * 8 + i;
    int b = r >> 10, nrow = r & 1023;
#pragma unroll
    for (int jj = 0; jj < 8; jj += 4) {
      int c = c0 + tx * 8 + jj;
      int which = c >> 9;
      int cc = c & 511;
      int h = cc >> 6, d = cc & 63;
      float* dst = (which == 0) ? qb : ((which == 1) ? kb : vb);
      float4 v4 = make_float4(acc[i][jj], acc[i][jj + 1], acc[i][jj + 2], acc[i][jj + 3]);
      *(float4*)&dst[(size_t)((((b << 3) + h) << 10) + nrow) * DH + d] = v4;
    }
  }
}

// ---------------- fused attention: dots + abs-score + softmax (no max needed) + PV ----------------
__global__ __launch_bounds__(256) void attn_kernel(const float* __restrict__ qg,
                                                   const float* __restrict__ kg,
                                                   const float* __restrict__ vg,
                                                   const int* __restrict__ mask,
                                                   float* __restrict__ oat,
                                                   float* __restrict__ sph) {
  int bh = blockIdx.y;        // 0..63
  int rb = blockIdx.x;        // 0..15
  int b = bh >> 3, h = bh & 7;
  int row0 = rb * 64;
  int t = threadIdx.x;
  int tx = t & 15, ty = t >> 4;
  int lane = t & 63, w = t >> 6;

  __shared__ float Qs[64][68];                // [d][r]
  __shared__ float Ks[64][68];                // [d][m]
  __shared__ float Vs[64][64];                // [m][d]
  __shared__ float Ps[64][68];                // [m][r]
  __shared__ unsigned long long Mb[64];       // mask bits per q-row for current m-tile

  // stage Q transposed (once)
  {
    int qr = t >> 4;
    int d0 = (t & 15) * 4;
#pragma unroll
    for (int p = 0; p < 4; ++p) {
      int r = p * 16 + qr;
      const float4 qv = *(const float4*)&qg[(size_t)(bh * NN + row0 + r) * DH + d0];
      Qs[d0 + 0][r] = qv.x;
      Qs[d0 + 1][r] = qv.y;
      Qs[d0 + 2][r] = qv.z;
      Qs[d0 + 3][r] = qv.w;
    }
  }

  float acc[4][4];
  float Lacc[4], Sacc[4];
#pragma unroll
  for (int i = 0; i < 4; ++i) {
    Lacc[i] = 0.f; Sacc[i] = 0.f;
#pragma unroll
    for (int j = 0; j < 4; ++j) acc[i][j] = 0.f;
  }

  int r0 = ty * 4;
  int mc0 = tx * 4;
  int d0v = tx * 4;

  for (int mt = 0; mt < 16; ++mt) {
    int m0 = mt * 64;
    // stage K (transposed), V (natural)
    {
      int mr = t >> 4;
      int d0 = (t & 15) * 4;
#pragma unroll
      for (int p = 0; p < 4; ++p) {
        int m = p * 16 + mr;
        const float4 kv = *(const float4*)&kg[(size_t)(bh * NN + m0 + m) * DH + d0];
        Ks[d0 + 0][m] = kv.x;
        Ks[d0 + 1][m] = kv.y;
        Ks[d0 + 2][m] = kv.z;
        Ks[d0 + 3][m] = kv.w;
        const float4 vv = *(const float4*)&vg[(size_t)(bh * NN + m0 + m) * DH + d0];
        *(float4*)&Vs[m][d0] = vv;
      }
      // mask bits: one wave per 16 rows, ballot across 64 m-columns
      for (int rr = 0; rr < 16; ++rr) {
        int r = w * 16 + rr;
        int mv = mask[(size_t)(row0 + r) * NN + m0 + lane];
        unsigned long long bits = __ballot(mv != 0);
        if (lane == 0) Mb[r] = bits;
      }
    }
    __syncthreads();

    // S = Q @ K^T (4x4 per thread)
    float s[4][4];
#pragma unroll
    for (int i = 0; i < 4; ++i)
#pragma unroll
      for (int j = 0; j < 4; ++j) s[i][j] = 0.f;
#pragma unroll 8
    for (int d = 0; d < 64; ++d) {
      float4 a4 = *(const float4*)&Qs[d][r0];
      float4 b4 = *(const float4*)&Ks[d][mc0];
      float af[4] = {a4.x, a4.y, a4.z, a4.w};
      float bf[4] = {b4.x, b4.y, b4.z, b4.w};
#pragma unroll
      for (int i = 0; i < 4; ++i)
#pragma unroll
        for (int j = 0; j < 4; ++j) s[i][j] = fmaf(af[i], bf[j], s[i][j]);
    }

    // softmax weights (exp, no max needed: |logit| <= ~1.5) + partial row sums
    unsigned long long mb[4];
#pragma unroll
    for (int i = 0; i < 4; ++i) mb[i] = Mb[r0 + i];
    float lsum[4], ssum[4];
#pragma unroll
    for (int i = 0; i < 4; ++i) {
      float ls = 0.f, ss = 0.f;
#pragma unroll
      for (int j = 0; j < 4; ++j) {
        float mf = ((mb[i] >> (mc0 + j)) & 1ULL) ? 1.0f : 0.0f;
        float sv = s[i][j];
        ss += fabsf(sv) * mf;
        float p = __expf(sv * SCALE * mf);
        s[i][j] = p;
        ls += p;
      }
      lsum[i] = ls; ssum[i] = ss;
    }
    // butterfly reduce across the 16 lanes covering this row group (deterministic)
#pragma unroll
    for (int off = 1; off < 16; off <<= 1) {
#pragma unroll
      for (int i = 0; i < 4; ++i) {
        lsum[i] += __shfl_xor(lsum[i], off, 16);
        ssum[i] += __shfl_xor(ssum[i], off, 16);
      }
    }
#pragma unroll
    for (int i = 0; i < 4; ++i) { Lacc[i] += lsum[i]; Sacc[i] += ssum[i]; }

    // write P (transposed: [m][r])
#pragma unroll
    for (int i = 0; i < 4; ++i)
#pragma unroll
      for (int j = 0; j < 4; ++j) Ps[mc0 + j][r0 + i] = s[i][j];
    __syncthreads();

    // acc += P^T @ V  (O[r][d], 4x4 per thread)
#pragma unroll 8
    for (int m = 0; m < 64; ++m) {
      float4 p4 = *(const float4*)&Ps[m][r0];
      float4 v4 = *(const float4*)&Vs[m][d0v];
      float pf[4] = {p4.x, p4.y, p4.z, p4.w};
      float vf[4] = {v4.x, v4.y, v4.z, v4.w};
#pragma unroll
      for (int i = 0; i < 4; ++i)
#pragma unroll
        for (int j = 0; j < 4; ++j) acc[i][j] = fmaf(pf[i], vf[j], acc[i][j]);
    }
    __syncthreads();
  }

  // epilogue: normalize and store out [b][n][h*64+d]; store per-head abs-score
#pragma unroll
  for (int i = 0; i < 4; ++i) {
    float inv = 1.0f / Lacc[i];
    float4 o = make_float4(acc[i][0] * inv, acc[i][1] * inv, acc[i][2] * inv, acc[i][3] * inv);
    *(float4*)&oat[(size_t)((b << 10) + row0 + r0 + i) * INNER + (h << 6) + d0v] = o;
  }
  if (tx == 0) {
#pragma unroll
    for (int i = 0; i < 4; ++i) sph[(size_t)(bh << 10) + row0 + r0 + i] = Sacc[i];
  }
}

// ---------------- score = 0.125 * sum_h sph / nnz ----------------
__global__ __launch_bounds__(256) void score_reduce(const float* __restrict__ sph,
                                                    const float* __restrict__ nnzf,
                                                    float* __restrict__ score) {
  int g = blockIdx.x * 256 + threadIdx.x;   // 0..8191
  int b = g >> 10, r = g & 1023;
  float s = 0.f;
#pragma unroll
  for (int h = 0; h < 8; ++h) s += sph[(size_t)(((b << 3) + h) << 10) + r];
  score[g] = SCALE * s / nnzf[r];
}

// ---------------- per-batch selection of (patches+1) smallest scores (stable ascending) ----------------
__global__ __launch_bounds__(256) void select_kernel(const float* __restrict__ score,
                                                     const int* __restrict__ pic_ptr,
                                                     int* __restrict__ asc) {
  int bb = blockIdx.x;
  int t = threadIdx.x;
  int cnt = pic_ptr[0] + 1;
  __shared__ float sv[1024];
  __shared__ float rv[256];
  __shared__ int ri[256];
  for (int i = t; i < 1024; i += 256) sv[i] = score[(size_t)bb * 1024 + i];
  __syncthreads();
  for (int sel = 0; sel < cnt; ++sel) {
    float bv = 3.4e38f; int bi = 1 << 30;
    for (int i = t; i < 1024; i += 256) {
      float v = sv[i];
      if (v < bv) { bv = v; bi = i; }   // ascending scan -> smallest index kept on ties
    }
    rv[t] = bv; ri[t] = bi;
    __syncthreads();
    for (int s2 = 128; s2 > 0; s2 >>= 1) {
      if (t < s2) {
        float ov = rv[t + s2]; int oi = ri[t + s2];
        if (ov < rv[t] || (ov == rv[t] && oi < ri[t])) { rv[t] = ov; ri[t] = oi; }
      }
      __syncthreads();
    }
    if (t == 0) {
      asc[bb * 32 + sel] = ri[0];
      sv[ri[0]] = 3.4e38f;
    }
    __syncthreads();
  }
}

// ---------------- build row-gather map replicating the sequential swap loop ----------------
__global__ __launch_bounds__(256) void build_src(const int* __restrict__ asc,
                                                 const int* __restrict__ pic_ptr,
                                                 int* __restrict__ src) {
  int bi = blockIdx.x;
  int t = threadIdx.x;
  for (int r = t; r < 1024; r += 256) src[bi * 1024 + r] = r;
  __syncthreads();
  if (t == 0) {
    int pic = pic_ptr[0];
    const int* a = &asc[(7 - bi) * 32];   // idx = argsort(score)[::-1] reverses BATCH axis
    for (int i = 1; i <= pic; ++i) {
      int ti = a[i];
      src[bi * 1024 + i] = ti;
      src[bi * 1024 + ti] = i;
    }
  }
}

// ---------------- out GEMM with fused row gather: C = gather(oat) @ w_out + b_out ----------------
__global__ __launch_bounds__(256) void out_gemm(const float* __restrict__ A,
                                                const float* __restrict__ B,
                                                const float* __restrict__ bias,
                                                const int* __restrict__ src,
                                                float* __restrict__ C) {
  __shared__ float As[16][132];
  __shared__ float Bs[16][128];
  int t = threadIdx.x;
  int tx = t & 15, ty = t >> 4;
  int r0 = blockIdx.y * 128;
  int c0 = blockIdx.x * 128;
  float acc[8][8];
#pragma unroll
  for (int i = 0; i < 8; ++i)
#pragma unroll
    for (int j = 0; j < 8; ++j) acc[i][j] = 0.f;

  int sar = t >> 2;
  int sak = (t & 3) * 4;
  int sbk = t >> 4;
  int sbc = (t & 15) * 8;
  int bb = r0 >> 10;                               // block never crosses a batch
  int g0 = (bb << 10) + src[r0 + sar];
  int g1 = (bb << 10) + src[r0 + 64 + sar];

  for (int kt = 0; kt < INNER; kt += 16) {
    {
      const float4 a0 = *(const float4*)&A[(size_t)g0 * INNER + kt + sak];
      As[sak + 0][sar] = a0.x;
      As[sak + 1][sar] = a0.y;
      As[sak + 2][sar] = a0.z;
      As[sak + 3][sar] = a0.w;
      const float4 a1 = *(const float4*)&A[(size_t)g1 * INNER + kt + sak];
      As[sak + 0][64 + sar] = a1.x;
      As[sak + 1][64 + sar] = a1.y;
      As[sak + 2][64 + sar] = a1.z;
      As[sak + 3][64 + sar] = a1.w;
    }
    {
      const float4 b0 = *(const float4*)&B[(size_t)(kt + sbk) * DIM + c0 + sbc];
      const float4 b1 = *(const float4*)&B[(size_t)(kt + sbk) * DIM + c0 + sbc + 4];
      *(float4*)&Bs[sbk][sbc] = b0;
      *(float4*)&Bs[sbk][sbc + 4] = b1;
    }
    __syncthreads();
#pragma unroll
    for (int kk = 0; kk < 16; ++kk) {
      float af[8], bf[8];
      *(float4*)&af[0] = *(const float4*)&As[kk][ty * 8];
      *(float4*)&af[4] = *(const float4*)&As[kk][ty * 8 + 4];
      *(float4*)&bf[0] = *(const float4*)&Bs[kk][tx * 8];
      *(float4*)&bf[4] = *(const float4*)&Bs[kk][tx * 8 + 4];
#pragma unroll
      for (int i = 0; i < 8; ++i)
#pragma unroll
        for (int j = 0; j < 8; ++j) acc[i][j] = fmaf(af[i], bf[j], acc[i][j]);
    }
    __syncthreads();
  }
  float4 bv0 = *(const float4*)&bias[c0 + tx * 8];
  float4 bv1 = *(const float4*)&bias[c0 + tx * 8 + 4];
#pragma unroll
  for (int i = 0; i < 8; ++i) {
    int r = r0 + ty * 8 + i;
    float4 o0 = make_float4(acc[i][0] + bv0.x, acc[i][1] + bv0.y, acc[i][2] + bv0.z, acc[i][3] + bv0.w);
    float4 o1 = make_float4(acc[i][4] + bv1.x, acc[i][5] + bv1.y, acc[i][6] + bv1.z, acc[i][7] + bv1.w);
    *(float4*)&C[(size_t)r * DIM + c0 + tx * 8] = o0;
    *(float4*)&C[(size_t)r * DIM + c0 + tx * 8 + 4] = o1;
  }
}

extern "C" void kernel_launch(void* const* d_in, const int* in_sizes, int n_in,
                              void* d_out, int out_size, void* d_ws, size_t ws_size,
                              hipStream_t stream) {
  const float* x      = (const float*)d_in[0];
  const int*   cpmask = (const int*)d_in[1];
  const float* w_qkv  = (const float*)d_in[2];
  const float* w_out  = (const float*)d_in[3];
  const float* b_out  = (const float*)d_in[4];
  const int*   pic    = (const int*)d_in[5];
  float* out = (float*)d_out;

  float* ws = (float*)d_ws;
  const size_t QKV_ELEMS = (size_t)64 * 1024 * 64;   // 4.19M floats each
  float* qb   = ws;
  float* kb   = qb + QKV_ELEMS;
  float* vb   = kb + QKV_ELEMS;
  float* oat  = vb + QKV_ELEMS;                      // 8192*512
  float* sph  = oat + (size_t)8192 * 512;            // 64*1024
  float* sc   = sph + 65536;                         // 8192
  float* nnzf = sc + 8192;                           // 1024
  int*   asc  = (int*)(nnzf + 1024);                 // 8*32
  int*   src  = asc + 512;                           // 8192
  // total ws use: ~67.5 MB

  hipLaunchKernelGGL(nnz_kernel,  dim3(1024),   dim3(64),  0, stream, cpmask, nnzf);
  hipLaunchKernelGGL(qkv_gemm,    dim3(12, 64), dim3(256), 0, stream, x, w_qkv, qb, kb, vb);
  hipLaunchKernelGGL(attn_kernel, dim3(16, 64), dim3(256), 0, stream, qb, kb, vb, cpmask, oat, sph);
  hipLaunchKernelGGL(score_reduce, dim3(32),    dim3(256), 0, stream, sph, nnzf, sc);
  hipLaunchKernelGGL(select_kernel, dim3(8),    dim3(256), 0, stream, sc, pic, asc);
  hipLaunchKernelGGL(build_src,   dim3(8),      dim3(256), 0, stream, asc, pic, src);
  hipLaunchKernelGGL(out_gemm,    dim3(4, 64),  dim3(256), 0, stream, oat, w_out, b_out, src, out);
}

// Round 2
// 430.922 us; speedup vs baseline: 1.5144x; 1.5144x over previous
//
#include <hip/hip_runtime.h>
#include <hip/hip_bf16.h>

#define NN 1024
#define DH 64
#define DIM 512
#define INNER 512
#define QKV_N 1536
#define SCALE 0.125f
#define PITCH 72   // shorts; 144B row stride: 16B-aligned for b128, bank-uniform

typedef short short8 __attribute__((ext_vector_type(8)));
typedef float floatx4 __attribute__((ext_vector_type(4)));

static __device__ __forceinline__ unsigned short f2bf(float x) {
  __hip_bfloat16 h = __float2bfloat16(x);
  unsigned short u;
  __builtin_memcpy(&u, &h, 2);
  return u;
}
// split fp32 into hi+lo bf16 planes: x ~= hi + lo, residual ~2^-18 * |x|
static __device__ __forceinline__ void splitbf(float x, unsigned short& hi, unsigned short& lo) {
  __hip_bfloat16 h = __float2bfloat16(x);
  float hf = __bfloat162float(h);
  __hip_bfloat16 l = __float2bfloat16(x - hf);
  __builtin_memcpy(&hi, &h, 2);
  __builtin_memcpy(&lo, &l, 2);
}

// ---------------- nnz + 64-col bitmasks per mask row ----------------
__global__ __launch_bounds__(64) void nnz_kernel(const int* __restrict__ mask,
                                                 float* __restrict__ nnzf,
                                                 unsigned long long* __restrict__ Mbits) {
  int row = blockIdx.x;
  int lane = threadIdx.x;
  const int* mrow = mask + (size_t)row * NN;
  int tot = 0;
  for (int mt = 0; mt < 16; ++mt) {
    unsigned long long bits = __ballot(mrow[mt * 64 + lane] != 0);
    if (lane == 0) {
      Mbits[(size_t)row * 16 + mt] = bits;
      tot += __popcll(bits);
    }
  }
  if (lane == 0) nnzf[row] = (float)tot;
}

// ---------------- QKV GEMM: x(8192x512) @ w_qkv(512x1536), scatter to per-head q/k/v ----------------
__global__ __launch_bounds__(256) void qkv_gemm(const float* __restrict__ A,
                                                const float* __restrict__ B,
                                                float* __restrict__ qb,
                                                float* __restrict__ kb,
                                                float* __restrict__ vb) {
  __shared__ float As[16][132];
  __shared__ float Bs[16][128];
  int t = threadIdx.x;
  int tx = t & 15, ty = t >> 4;
  int r0 = blockIdx.y * 128;
  int c0 = blockIdx.x * 128;
  float acc[8][8];
#pragma unroll
  for (int i = 0; i < 8; ++i)
#pragma unroll
    for (int j = 0; j < 8; ++j) acc[i][j] = 0.f;

  int sar = t >> 2;
  int sak = (t & 3) * 4;
  int sbk = t >> 4;
  int sbc = (t & 15) * 8;

  for (int kt = 0; kt < DIM; kt += 16) {
#pragma unroll
    for (int p = 0; p < 2; ++p) {
      int ar = p * 64 + sar;
      const float4 av = *(const float4*)&A[(size_t)(r0 + ar) * DIM + kt + sak];
      As[sak + 0][ar] = av.x;
      As[sak + 1][ar] = av.y;
      As[sak + 2][ar] = av.z;
      As[sak + 3][ar] = av.w;
    }
    {
      const float4 b0 = *(const float4*)&B[(size_t)(kt + sbk) * QKV_N + c0 + sbc];
      const float4 b1 = *(const float4*)&B[(size_t)(kt + sbk) * QKV_N + c0 + sbc + 4];
      *(float4*)&Bs[sbk][sbc] = b0;
      *(float4*)&Bs[sbk][sbc + 4] = b1;
    }
    __syncthreads();
#pragma unroll
    for (int kk = 0; kk < 16; ++kk) {
      float af[8], bf[8];
      *(float4*)&af[0] = *(const float4*)&As[kk][ty * 8];
      *(float4*)&af[4] = *(const float4*)&As[kk][ty * 8 + 4];
      *(float4*)&bf[0] = *(const float4*)&Bs[kk][tx * 8];
      *(float4*)&bf[4] = *(const float4*)&Bs[kk][tx * 8 + 4];
#pragma unroll
      for (int i = 0; i < 8; ++i)
#pragma unroll
        for (int j = 0; j < 8; ++j) acc[i][j] = fmaf(af[i], bf[j], acc[i][j]);
    }
    __syncthreads();
  }
#pragma unroll
  for (int i = 0; i < 8; ++i) {
    int r = r0 + ty * 8 + i;
    int b = r >> 10, nrow = r & 1023;
#pragma unroll
    for (int jj = 0; jj < 8; jj += 4) {
      int c = c0 + tx * 8 + jj;
      int which = c >> 9;
      int cc = c & 511;
      int h = cc >> 6, d = cc & 63;
      float* dst = (which == 0) ? qb : ((which == 1) ? kb : vb);
      float4 v4 = make_float4(acc[i][jj], acc[i][jj + 1], acc[i][jj + 2], acc[i][jj + 3]);
      *(float4*)&dst[(size_t)((((b << 3) + h) << 10) + nrow) * DH + d] = v4;
    }
  }
}

// ---------------- MFMA flash attention: split-bf16 QK^T + bf16 PV ----------------
// block = 256 (4 waves); grid = (16 row-tiles, 64 bh). Wave w owns q-rows 16w..16w+15.
__global__ __launch_bounds__(256, 4) void attn_kernel(const float* __restrict__ qg,
                                                      const float* __restrict__ kg,
                                                      const float* __restrict__ vg,
                                                      const unsigned long long* __restrict__ Mbits,
                                                      float* __restrict__ oat,
                                                      float* __restrict__ sph) {
  int bh = blockIdx.y;
  int rb = blockIdx.x;
  int b = bh >> 3, h = bh & 7;
  int row0 = rb * 64;
  int t = threadIdx.x;
  int lane = t & 63, w = t >> 6;
  int q4 = lane >> 4;       // quad
  int s = lane & 15;
  int gr = 16 * w + s;      // A-fragment row (this wave's strip)

  // 4 bf16 planes (64 x PITCH) + mask bits. Aliasing: Ps<=Qhi, Vt<=Qlo
  // (Q planes are only read into registers before the main loop).
  __shared__ __align__(16) unsigned short smem[4 * 64 * PITCH];
  __shared__ unsigned long long Mb[64];
  typedef unsigned short (*plane_t)[PITCH];
  plane_t Qhi = (plane_t)(smem);
  plane_t Qlo = (plane_t)(smem + 64 * PITCH);
  plane_t Khi = (plane_t)(smem + 2 * 64 * PITCH);
  plane_t Klo = (plane_t)(smem + 3 * 64 * PITCH);
  plane_t Ps  = Qhi;
  plane_t Vt  = Qlo;

  // ---- stage Q hi/lo (each wave stages exactly its own 16-row strip: t>>2 in [16w,16w+16)) ----
  {
    int r = t >> 2, d0 = (t & 3) * 16;
    const float* srcq = &qg[(size_t)(bh * NN + row0 + r) * DH + d0];
#pragma unroll
    for (int c = 0; c < 16; c += 4) {
      float4 v = *(const float4*)&srcq[c];
      ushort4 h4, l4;
      splitbf(v.x, h4.x, l4.x);
      splitbf(v.y, h4.y, l4.y);
      splitbf(v.z, h4.z, l4.z);
      splitbf(v.w, h4.w, l4.w);
      *(ushort4*)&Qhi[r][d0 + c] = h4;
      *(ushort4*)&Qlo[r][d0 + c] = l4;
    }
  }
  // hoist Q fragments (invariant over m-tiles); intra-wave LDS ordering suffices
  short8 aqh[2], aql[2];
#pragma unroll
  for (int ks = 0; ks < 2; ++ks) {
    int d0 = ks * 32 + q4 * 8;
    aqh[ks] = *(const short8*)&Qhi[gr][d0];
    aql[ks] = *(const short8*)&Qlo[gr][d0];
  }

  floatx4 Oacc[4];
  float Lacc[4], Sco[4];
#pragma unroll
  for (int j = 0; j < 4; ++j) { Oacc[j][0] = 0.f; Oacc[j][1] = 0.f; Oacc[j][2] = 0.f; Oacc[j][3] = 0.f; }
#pragma unroll
  for (int i = 0; i < 4; ++i) { Lacc[i] = 0.f; Sco[i] = 0.f; }

  for (int mt = 0; mt < 16; ++mt) {
    int m0 = mt * 64;
    __syncthreads();   // everyone done reading K/V/Mb of previous tile (covers Q-frag hoist at mt=0)
    // ---- stage K hi/lo, V transposed (bf16), mask bits ----
    {
      int r = t >> 2, d0 = (t & 3) * 16;
      const float* srck = &kg[(size_t)(bh * NN + m0 + r) * DH + d0];
#pragma unroll
      for (int c = 0; c < 16; c += 4) {
        float4 v = *(const float4*)&srck[c];
        ushort4 h4, l4;
        splitbf(v.x, h4.x, l4.x);
        splitbf(v.y, h4.y, l4.y);
        splitbf(v.z, h4.z, l4.z);
        splitbf(v.w, h4.w, l4.w);
        *(ushort4*)&Khi[r][d0 + c] = h4;
        *(ushort4*)&Klo[r][d0 + c] = l4;
      }
      const float* srcv = &vg[(size_t)(bh * NN + m0 + r) * DH + d0];
#pragma unroll
      for (int c = 0; c < 16; c += 4) {
        float4 v = *(const float4*)&srcv[c];
        Vt[d0 + c + 0][r] = f2bf(v.x);
        Vt[d0 + c + 1][r] = f2bf(v.y);
        Vt[d0 + c + 2][r] = f2bf(v.z);
        Vt[d0 + c + 3][r] = f2bf(v.w);
      }
      if (t < 64) Mb[t] = Mbits[(size_t)(row0 + t) * 16 + mt];
    }
    __syncthreads();

    // ---- S = Q K^T via 3-MFMA split accumulation ----
    floatx4 Sf[4];
#pragma unroll
    for (int j = 0; j < 4; ++j) { Sf[j][0] = 0.f; Sf[j][1] = 0.f; Sf[j][2] = 0.f; Sf[j][3] = 0.f; }
#pragma unroll
    for (int ks = 0; ks < 2; ++ks) {
      int d0 = ks * 32 + q4 * 8;
#pragma unroll
      for (int j = 0; j < 4; ++j) {
        int n = 16 * j + s;
        short8 bh8 = *(const short8*)&Khi[n][d0];
        short8 bl8 = *(const short8*)&Klo[n][d0];
        Sf[j] = __builtin_amdgcn_mfma_f32_16x16x32_bf16(aql[ks], bh8, Sf[j], 0, 0, 0);
        Sf[j] = __builtin_amdgcn_mfma_f32_16x16x32_bf16(aqh[ks], bl8, Sf[j], 0, 0, 0);
        Sf[j] = __builtin_amdgcn_mfma_f32_16x16x32_bf16(aqh[ks], bh8, Sf[j], 0, 0, 0);
      }
    }

    // ---- softmax weights (exp, no max-sub: |logit|<=~1.5), abs-score, row sums ----
    unsigned long long mb[4];
#pragma unroll
    for (int i = 0; i < 4; ++i) mb[i] = Mb[16 * w + 4 * q4 + i];
    float lsum[4], ssum[4];
#pragma unroll
    for (int i = 0; i < 4; ++i) { lsum[i] = 0.f; ssum[i] = 0.f; }
    unsigned short pw[4][4];
#pragma unroll
    for (int j = 0; j < 4; ++j) {
#pragma unroll
      for (int i = 0; i < 4; ++i) {
        float sv = Sf[j][i];
        float mf = ((mb[i] >> (16 * j + s)) & 1ULL) ? 1.0f : 0.0f;
        ssum[i] += fabsf(sv) * mf;
        float p = __expf(sv * SCALE * mf);
        lsum[i] += p;
        pw[i][j] = f2bf(p);
      }
    }
#pragma unroll
    for (int off = 1; off < 16; off <<= 1) {
#pragma unroll
      for (int i = 0; i < 4; ++i) {
        lsum[i] += __shfl_xor(lsum[i], off, 16);
        ssum[i] += __shfl_xor(ssum[i], off, 16);
      }
    }
#pragma unroll
    for (int i = 0; i < 4; ++i) { Lacc[i] += lsum[i]; Sco[i] += ssum[i]; }

    // ---- P round-trip through LDS (C-layout -> A-layout), strictly intra-wave rows ----
#pragma unroll
    for (int i = 0; i < 4; ++i)
#pragma unroll
      for (int j = 0; j < 4; ++j) Ps[16 * w + 4 * q4 + i][16 * j + s] = pw[i][j];
    // no barrier needed: Ps rows written & read only by this wave; Vt covered by stage barrier

    // ---- O += P V ----
#pragma unroll
    for (int ks = 0; ks < 2; ++ks) {
      int mm0 = ks * 32 + q4 * 8;
      short8 ap = *(const short8*)&Ps[gr][mm0];
#pragma unroll
      for (int j = 0; j < 4; ++j) {
        short8 bv = *(const short8*)&Vt[16 * j + s][mm0];
        Oacc[j] = __builtin_amdgcn_mfma_f32_16x16x32_bf16(ap, bv, Oacc[j], 0, 0, 0);
      }
    }
  }

  // ---- epilogue: normalize, store out-attn [b][n][h*64+d]; per-head abs score ----
#pragma unroll
  for (int i = 0; i < 4; ++i) {
    int r = row0 + 16 * w + 4 * q4 + i;
    float iv = 1.0f / Lacc[i];
#pragma unroll
    for (int j = 0; j < 4; ++j)
      oat[(size_t)((b << 10) + r) * INNER + (h << 6) + 16 * j + s] = Oacc[j][i] * iv;
    if (s == 0) sph[((size_t)bh << 10) + r] = Sco[i];
  }
}

// ---------------- score = 0.125 * sum_h sph / nnz ----------------
__global__ __launch_bounds__(256) void score_reduce(const float* __restrict__ sph,
                                                    const float* __restrict__ nnzf,
                                                    float* __restrict__ score) {
  int g = blockIdx.x * 256 + threadIdx.x;
  int b = g >> 10, r = g & 1023;
  float sv = 0.f;
#pragma unroll
  for (int h = 0; h < 8; ++h) sv += sph[(size_t)(((b << 3) + h) << 10) + r];
  score[g] = SCALE * sv / nnzf[r];
}

// ---------------- per-batch selection of (patches+1) smallest scores ----------------
__global__ __launch_bounds__(256) void select_kernel(const float* __restrict__ score,
                                                     const int* __restrict__ pic_ptr,
                                                     int* __restrict__ asc) {
  int bb = blockIdx.x;
  int t = threadIdx.x;
  int cnt = pic_ptr[0] + 1;
  __shared__ float sv[1024];
  __shared__ float rv[256];
  __shared__ int ri[256];
  for (int i = t; i < 1024; i += 256) sv[i] = score[(size_t)bb * 1024 + i];
  __syncthreads();
  for (int sel = 0; sel < cnt; ++sel) {
    float bv = 3.4e38f; int bi = 1 << 30;
    for (int i = t; i < 1024; i += 256) {
      float v = sv[i];
      if (v < bv) { bv = v; bi = i; }
    }
    rv[t] = bv; ri[t] = bi;
    __syncthreads();
    for (int s2 = 128; s2 > 0; s2 >>= 1) {
      if (t < s2) {
        float ov = rv[t + s2]; int oi = ri[t + s2];
        if (ov < rv[t] || (ov == rv[t] && oi < ri[t])) { rv[t] = ov; ri[t] = oi; }
      }
      __syncthreads();
    }
    if (t == 0) {
      asc[bb * 32 + sel] = ri[0];
      sv[ri[0]] = 3.4e38f;
    }
    __syncthreads();
  }
}

// ---------------- build row-gather map replicating the sequential swap loop ----------------
__global__ __launch_bounds__(256) void build_src(const int* __restrict__ asc,
                                                 const int* __restrict__ pic_ptr,
                                                 int* __restrict__ src) {
  int bi = blockIdx.x;
  int t = threadIdx.x;
  for (int r = t; r < 1024; r += 256) src[bi * 1024 + r] = r;
  __syncthreads();
  if (t == 0) {
    int pic = pic_ptr[0];
    const int* a = &asc[(7 - bi) * 32];   // [::-1] reverses the BATCH axis
    for (int i = 1; i <= pic; ++i) {
      int ti = a[i];
      src[bi * 1024 + i] = ti;
      src[bi * 1024 + ti] = i;
    }
  }
}

// ---------------- out GEMM with fused row gather ----------------
__global__ __launch_bounds__(256) void out_gemm(const float* __restrict__ A,
                                                const float* __restrict__ B,
                                                const float* __restrict__ bias,
                                                const int* __restrict__ src,
                                                float* __restrict__ C) {
  __shared__ float As[16][132];
  __shared__ float Bs[16][128];
  int t = threadIdx.x;
  int tx = t & 15, ty = t >> 4;
  int r0 = blockIdx.y * 128;
  int c0 = blockIdx.x * 128;
  float acc[8][8];
#pragma unroll
  for (int i = 0; i < 8; ++i)
#pragma unroll
    for (int j = 0; j < 8; ++j) acc[i][j] = 0.f;

  int sar = t >> 2;
  int sak = (t & 3) * 4;
  int sbk = t >> 4;
  int sbc = (t & 15) * 8;
  int bb = r0 >> 10;
  int g0 = (bb << 10) + src[r0 + sar];
  int g1 = (bb << 10) + src[r0 + 64 + sar];

  for (int kt = 0; kt < INNER; kt += 16) {
    {
      const float4 a0 = *(const float4*)&A[(size_t)g0 * INNER + kt + sak];
      As[sak + 0][sar] = a0.x;
      As[sak + 1][sar] = a0.y;
      As[sak + 2][sar] = a0.z;
      As[sak + 3][sar] = a0.w;
      const float4 a1 = *(const float4*)&A[(size_t)g1 * INNER + kt + sak];
      As[sak + 0][64 + sar] = a1.x;
      As[sak + 1][64 + sar] = a1.y;
      As[sak + 2][64 + sar] = a1.z;
      As[sak + 3][64 + sar] = a1.w;
    }
    {
      const float4 b0 = *(const float4*)&B[(size_t)(kt + sbk) * DIM + c0 + sbc];
      const float4 b1 = *(const float4*)&B[(size_t)(kt + sbk) * DIM + c0 + sbc + 4];
      *(float4*)&Bs[sbk][sbc] = b0;
      *(float4*)&Bs[sbk][sbc + 4] = b1;
    }
    __syncthreads();
#pragma unroll
    for (int kk = 0; kk < 16; ++kk) {
      float af[8], bf[8];
      *(float4*)&af[0] = *(const float4*)&As[kk][ty * 8];
      *(float4*)&af[4] = *(const float4*)&As[kk][ty * 8 + 4];
      *(float4*)&bf[0] = *(const float4*)&Bs[kk][tx * 8];
      *(float4*)&bf[4] = *(const float4*)&Bs[kk][tx * 8 + 4];
#pragma unroll
      for (int i = 0; i < 8; ++i)
#pragma unroll
        for (int j = 0; j < 8; ++j) acc[i][j] = fmaf(af[i], bf[j], acc[i][j]);
    }
    __syncthreads();
  }
  float4 bv0 = *(const float4*)&bias[c0 + tx * 8];
  float4 bv1 = *(const float4*)&bias[c0 + tx * 8 + 4];
#pragma unroll
  for (int i = 0; i < 8; ++i) {
    int r = r0 + ty * 8 + i;
    float4 o0 = make_float4(acc[i][0] + bv0.x, acc[i][1] + bv0.y, acc[i][2] + bv0.z, acc[i][3] + bv0.w);
    float4 o1 = make_float4(acc[i][4] + bv1.x, acc[i][5] + bv1.y, acc[i][6] + bv1.z, acc[i][7] + bv1.w);
    *(float4*)&C[(size_t)r * DIM + c0 + tx * 8] = o0;
    *(float4*)&C[(size_t)r * DIM + c0 + tx * 8 + 4] = o1;
  }
}

extern "C" void kernel_launch(void* const* d_in, const int* in_sizes, int n_in,
                              void* d_out, int out_size, void* d_ws, size_t ws_size,
                              hipStream_t stream) {
  const float* x      = (const float*)d_in[0];
  const int*   cpmask = (const int*)d_in[1];
  const float* w_qkv  = (const float*)d_in[2];
  const float* w_out  = (const float*)d_in[3];
  const float* b_out  = (const float*)d_in[4];
  const int*   pic    = (const int*)d_in[5];
  float* out = (float*)d_out;

  float* ws = (float*)d_ws;
  const size_t QKV_ELEMS = (size_t)64 * 1024 * 64;
  float* qb   = ws;
  float* kb   = qb + QKV_ELEMS;
  float* vb   = kb + QKV_ELEMS;
  float* oat  = vb + QKV_ELEMS;
  float* sph  = oat + (size_t)8192 * 512;
  float* sc   = sph + 65536;
  float* nnzf = sc + 8192;
  int*   asc  = (int*)(nnzf + 1024);
  int*   src  = asc + 512;
  unsigned long long* Mbits = (unsigned long long*)(src + 8192);  // 1024*16 u64, 8B-aligned

  hipLaunchKernelGGL(nnz_kernel,   dim3(1024),   dim3(64),  0, stream, cpmask, nnzf, Mbits);
  hipLaunchKernelGGL(qkv_gemm,     dim3(12, 64), dim3(256), 0, stream, x, w_qkv, qb, kb, vb);
  hipLaunchKernelGGL(attn_kernel,  dim3(16, 64), dim3(256), 0, stream, qb, kb, vb, Mbits, oat, sph);
  hipLaunchKernelGGL(score_reduce, dim3(32),     dim3(256), 0, stream, sph, nnzf, sc);
  hipLaunchKernelGGL(select_kernel, dim3(8),     dim3(256), 0, stream, sc, pic, asc);
  hipLaunchKernelGGL(build_src,    dim3(8),      dim3(256), 0, stream, asc, pic, src);
  hipLaunchKernelGGL(out_gemm,     dim3(4, 64),  dim3(256), 0, stream, oat, w_out, b_out, src, out);
}

// Round 3
// 270.541 us; speedup vs baseline: 2.4121x; 1.5928x over previous
//
#include <hip/hip_runtime.h>
#include <hip/hip_bf16.h>

#define NN 1024
#define DH 64
#define DIM 512
#define INNER 512
#define QKV_N 1536
#define SCALE 0.125f
#define KPITCH 72   // shorts; K/Ps planes in attn
#define VPITCH 68   // shorts; Vt plane (8B-aligned rows, conflict-free transpose stores)
#define GPITCH 40   // shorts; GEMM LDS tiles [128][GPITCH], BK=32

typedef short short8 __attribute__((ext_vector_type(8)));
typedef short short4v __attribute__((ext_vector_type(4)));
typedef float floatx4 __attribute__((ext_vector_type(4)));

static __device__ __forceinline__ unsigned short f2bf(float x) {
  __hip_bfloat16 h = __float2bfloat16(x);
  unsigned short u;
  __builtin_memcpy(&u, &h, 2);
  return u;
}
static __device__ __forceinline__ void splitbf(float x, unsigned short& hi, unsigned short& lo) {
  __hip_bfloat16 h = __float2bfloat16(x);
  float hf = __bfloat162float(h);
  __hip_bfloat16 l = __float2bfloat16(x - hf);
  __builtin_memcpy(&hi, &h, 2);
  __builtin_memcpy(&lo, &l, 2);
}

// ---------------- nnz + 64-col bitmasks per mask row ----------------
__global__ __launch_bounds__(64) void nnz_kernel(const int* __restrict__ mask,
                                                 float* __restrict__ nnzf,
                                                 unsigned long long* __restrict__ Mbits) {
  int row = blockIdx.x;
  int lane = threadIdx.x;
  const int* mrow = mask + (size_t)row * NN;
  int tot = 0;
  for (int mt = 0; mt < 16; ++mt) {
    unsigned long long bits = __ballot(mrow[mt * 64 + lane] != 0);
    if (lane == 0) {
      Mbits[(size_t)row * 16 + mt] = bits;
      tot += __popcll(bits);
    }
  }
  if (lane == 0) nnzf[row] = (float)tot;
}

// ---------------- split fp32 -> hi/lo bf16 (elementwise, float4 granularity) ----------------
__global__ __launch_bounds__(256) void split_kernel(const float* __restrict__ in,
                                                    unsigned short* __restrict__ hi,
                                                    unsigned short* __restrict__ lo,
                                                    int n4) {
  int i = blockIdx.x * 256 + threadIdx.x;
  if (i >= n4) return;
  float4 v = ((const float4*)in)[i];
  ushort4 h, l;
  splitbf(v.x, h.x, l.x);
  splitbf(v.y, h.y, l.y);
  splitbf(v.z, h.z, l.z);
  splitbf(v.w, h.w, l.w);
  ((ushort4*)hi)[i] = h;
  ((ushort4*)lo)[i] = l;
}

// ---------------- transpose + split: in [K][N] fp32 -> hiT/loT [N][K] bf16 ----------------
__global__ __launch_bounds__(256) void tsplit_kernel(const float* __restrict__ in, int K, int N,
                                                     unsigned short* __restrict__ hiT,
                                                     unsigned short* __restrict__ loT) {
  __shared__ float tile[32][33];
  int n0 = blockIdx.x * 32, k0 = blockIdx.y * 32;
  int t = threadIdx.x;
  int tn = t & 31, tk = t >> 5;   // 32 x 8
#pragma unroll
  for (int i = 0; i < 32; i += 8)
    tile[tk + i][tn] = in[(size_t)(k0 + tk + i) * N + n0 + tn];
  __syncthreads();
#pragma unroll
  for (int i = 0; i < 32; i += 8) {
    int n = tk + i;
    float v = tile[tn][n];   // = in[k0+tn][n0+n]
    unsigned short h, l;
    splitbf(v, h, l);
    hiT[(size_t)(n0 + n) * K + k0 + tn] = h;
    loT[(size_t)(n0 + n) * K + k0 + tn] = l;
  }
}

// ---------------- QKV GEMM (split-bf16 MFMA): x(8192x512) @ w_qkv -> per-head split q/k, bf16 v ----------------
__global__ __launch_bounds__(256) void qkv_mfma(const unsigned short* __restrict__ xhi,
                                                const unsigned short* __restrict__ xlo,
                                                const unsigned short* __restrict__ bhiT,
                                                const unsigned short* __restrict__ bloT,
                                                unsigned short* __restrict__ qhi,
                                                unsigned short* __restrict__ qlo,
                                                unsigned short* __restrict__ khi,
                                                unsigned short* __restrict__ klo,
                                                unsigned short* __restrict__ vb) {
  __shared__ __align__(16) unsigned short Ah[128][GPITCH], Al[128][GPITCH];
  __shared__ __align__(16) unsigned short Bh[128][GPITCH], Bl[128][GPITCH];
  int t = threadIdx.x;
  int lane = t & 63, w = t >> 6;
  int wr = w >> 1, wc = w & 1;
  int s = lane & 15, q4 = lane >> 4;
  int r0 = blockIdx.y * 128, c0 = blockIdx.x * 128;

  floatx4 acc[4][4];
#pragma unroll
  for (int mi = 0; mi < 4; ++mi)
#pragma unroll
    for (int ni = 0; ni < 4; ++ni) { acc[mi][ni][0] = 0.f; acc[mi][ni][1] = 0.f; acc[mi][ni][2] = 0.f; acc[mi][ni][3] = 0.f; }

  for (int kt = 0; kt < DIM; kt += 32) {
    __syncthreads();
#pragma unroll
    for (int p = 0; p < 2; ++p) {
      int idx = p * 256 + t;
      int row = idx >> 2, kc = (idx & 3) * 8;
      *(short8*)&Ah[row][kc] = *(const short8*)&xhi[(size_t)(r0 + row) * DIM + kt + kc];
      *(short8*)&Al[row][kc] = *(const short8*)&xlo[(size_t)(r0 + row) * DIM + kt + kc];
      *(short8*)&Bh[row][kc] = *(const short8*)&bhiT[(size_t)(c0 + row) * DIM + kt + kc];
      *(short8*)&Bl[row][kc] = *(const short8*)&bloT[(size_t)(c0 + row) * DIM + kt + kc];
    }
    __syncthreads();
    short8 ah[4], al[4], bhf[4], blf[4];
#pragma unroll
    for (int mi = 0; mi < 4; ++mi) {
      ah[mi] = *(const short8*)&Ah[wr * 64 + mi * 16 + s][q4 * 8];
      al[mi] = *(const short8*)&Al[wr * 64 + mi * 16 + s][q4 * 8];
    }
#pragma unroll
    for (int ni = 0; ni < 4; ++ni) {
      bhf[ni] = *(const short8*)&Bh[wc * 64 + ni * 16 + s][q4 * 8];
      blf[ni] = *(const short8*)&Bl[wc * 64 + ni * 16 + s][q4 * 8];
    }
#pragma unroll
    for (int mi = 0; mi < 4; ++mi)
#pragma unroll
      for (int ni = 0; ni < 4; ++ni) {
        acc[mi][ni] = __builtin_amdgcn_mfma_f32_16x16x32_bf16(al[mi], bhf[ni], acc[mi][ni], 0, 0, 0);
        acc[mi][ni] = __builtin_amdgcn_mfma_f32_16x16x32_bf16(ah[mi], blf[ni], acc[mi][ni], 0, 0, 0);
        acc[mi][ni] = __builtin_amdgcn_mfma_f32_16x16x32_bf16(ah[mi], bhf[ni], acc[mi][ni], 0, 0, 0);
      }
  }

  int which = c0 >> 9;   // 0=q, 1=k, 2=v (block never crosses boundary)
#pragma unroll
  for (int mi = 0; mi < 4; ++mi)
#pragma unroll
    for (int ni = 0; ni < 4; ++ni) {
      int Cl = c0 + wc * 64 + ni * 16 + s;
      int cc = Cl & 511, h = cc >> 6, d = cc & 63;
#pragma unroll
      for (int i = 0; i < 4; ++i) {
        int R = r0 + wr * 64 + mi * 16 + q4 * 4 + i;
        int b = R >> 10, n = R & 1023;
        size_t o = (size_t)((((b << 3) + h) << 10) + n) * DH + d;
        float v = acc[mi][ni][i];
        if (which == 0) {
          unsigned short hh, ll;
          splitbf(SCALE * v, hh, ll);   // fold softmax scale into q (exact pow2)
          qhi[o] = hh; qlo[o] = ll;
        } else if (which == 1) {
          unsigned short hh, ll;
          splitbf(v, hh, ll);
          khi[o] = hh; klo[o] = ll;
        } else {
          vb[o] = f2bf(v);
        }
      }
    }
}

// ---------------- MFMA flash attention: bf16 planes in, split-bf16 O out ----------------
__global__ __launch_bounds__(256, 4) void attn_kernel(const unsigned short* __restrict__ qhi,
                                                      const unsigned short* __restrict__ qlo,
                                                      const unsigned short* __restrict__ khi,
                                                      const unsigned short* __restrict__ klo,
                                                      const unsigned short* __restrict__ vb,
                                                      const unsigned long long* __restrict__ Mbits,
                                                      unsigned short* __restrict__ ohi,
                                                      unsigned short* __restrict__ olo,
                                                      float* __restrict__ sph) {
  int bh = blockIdx.y;
  int rb = blockIdx.x;
  int b = bh >> 3, h = bh & 7;
  int row0 = rb * 64;
  int t = threadIdx.x;
  int lane = t & 63, w = t >> 6;
  int q4 = lane >> 4, s = lane & 15;
  int gr = 16 * w + s;

  __shared__ __align__(16) unsigned short Khs[64][KPITCH], Kls[64][KPITCH];
  __shared__ __align__(16) unsigned short Vts[64][VPITCH];
  __shared__ __align__(16) unsigned short Pss[64][KPITCH];
  __shared__ unsigned long long Mb[64];

  // Q fragments: direct global->register (pre-scaled, pre-split by qkv epilogue)
  short8 aqh[2], aql[2];
  {
    size_t qb0 = ((size_t)bh * NN + row0 + gr) * DH;
#pragma unroll
    for (int ks = 0; ks < 2; ++ks) {
      aqh[ks] = *(const short8*)&qhi[qb0 + ks * 32 + q4 * 8];
      aql[ks] = *(const short8*)&qlo[qb0 + ks * 32 + q4 * 8];
    }
  }

  floatx4 Oacc[4];
  float Lacc[4], Sco[4];
#pragma unroll
  for (int j = 0; j < 4; ++j) { Oacc[j][0] = 0.f; Oacc[j][1] = 0.f; Oacc[j][2] = 0.f; Oacc[j][3] = 0.f; }
#pragma unroll
  for (int i = 0; i < 4; ++i) { Lacc[i] = 0.f; Sco[i] = 0.f; }

  for (int mt = 0; mt < 16; ++mt) {
    int m0 = mt * 64;
    __syncthreads();
    // ---- stage K hi/lo (copy), V (transposed scalar stores), mask bits ----
#pragma unroll
    for (int p = 0; p < 2; ++p) {
      int idx = p * 256 + t;
      int n = idx >> 3, c8 = (idx & 7) * 8;
      size_t g = ((size_t)bh * NN + m0 + n) * DH + c8;
      *(short8*)&Khs[n][c8] = *(const short8*)&khi[g];
      *(short8*)&Kls[n][c8] = *(const short8*)&klo[g];
      short8 vv = *(const short8*)&vb[g];
#pragma unroll
      for (int j = 0; j < 8; ++j) Vts[c8 + j][n] = (unsigned short)vv[j];
    }
    if (t < 64) Mb[t] = Mbits[(size_t)(row0 + t) * 16 + mt];
    __syncthreads();

    // ---- S = Q K^T (3-MFMA split; logits already scaled) ----
    floatx4 Sf[4];
#pragma unroll
    for (int j = 0; j < 4; ++j) { Sf[j][0] = 0.f; Sf[j][1] = 0.f; Sf[j][2] = 0.f; Sf[j][3] = 0.f; }
#pragma unroll
    for (int ks = 0; ks < 2; ++ks) {
      int d0 = ks * 32 + q4 * 8;
#pragma unroll
      for (int j = 0; j < 4; ++j) {
        short8 kh8 = *(const short8*)&Khs[16 * j + s][d0];
        short8 kl8 = *(const short8*)&Kls[16 * j + s][d0];
        Sf[j] = __builtin_amdgcn_mfma_f32_16x16x32_bf16(aql[ks], kh8, Sf[j], 0, 0, 0);
        Sf[j] = __builtin_amdgcn_mfma_f32_16x16x32_bf16(aqh[ks], kl8, Sf[j], 0, 0, 0);
        Sf[j] = __builtin_amdgcn_mfma_f32_16x16x32_bf16(aqh[ks], kh8, Sf[j], 0, 0, 0);
      }
    }

    // ---- softmax weights + deferred per-lane L/S partials ----
    unsigned long long mb[4];
#pragma unroll
    for (int i = 0; i < 4; ++i) mb[i] = Mb[16 * w + 4 * q4 + i];
    unsigned short pw[4][4];
#pragma unroll
    for (int j = 0; j < 4; ++j) {
#pragma unroll
      for (int i = 0; i < 4; ++i) {
        float sv = Sf[j][i];
        float mf = ((mb[i] >> (16 * j + s)) & 1ULL) ? 1.0f : 0.0f;
        Sco[i] += fabsf(sv) * mf;          // |scaled dot| (SCALE folded into q)
        float p = __expf(sv * mf);         // masked -> exp(0)=1, matches reference
        Lacc[i] += p;
        pw[i][j] = f2bf(p);
      }
    }

    // ---- P: C-layout -> A-layout via intra-wave LDS round-trip ----
#pragma unroll
    for (int i = 0; i < 4; ++i)
#pragma unroll
      for (int j = 0; j < 4; ++j) Pss[16 * w + 4 * q4 + i][16 * j + s] = pw[i][j];

    // ---- O += P V ----
#pragma unroll
    for (int ks = 0; ks < 2; ++ks) {
      int mm0 = ks * 32 + q4 * 8;
      short8 ap = *(const short8*)&Pss[gr][mm0];
#pragma unroll
      for (int j = 0; j < 4; ++j) {
        short8 bv;
        *(short4v*)&bv = *(const short4v*)&Vts[16 * j + s][mm0];
        *(((short4v*)&bv) + 1) = *(const short4v*)&Vts[16 * j + s][mm0 + 4];
        Oacc[j] = __builtin_amdgcn_mfma_f32_16x16x32_bf16(ap, bv, Oacc[j], 0, 0, 0);
      }
    }
  }

  // ---- final cross-lane reduction (once), epilogue ----
#pragma unroll
  for (int off = 1; off < 16; off <<= 1) {
#pragma unroll
    for (int i = 0; i < 4; ++i) {
      Lacc[i] += __shfl_xor(Lacc[i], off, 16);
      Sco[i] += __shfl_xor(Sco[i], off, 16);
    }
  }
#pragma unroll
  for (int i = 0; i < 4; ++i) {
    int r = row0 + 16 * w + 4 * q4 + i;
    float iv = 1.0f / Lacc[i];
#pragma unroll
    for (int j = 0; j < 4; ++j) {
      float o = Oacc[j][i] * iv;
      unsigned short hh, ll;
      splitbf(o, hh, ll);
      size_t oo = (size_t)((b << 10) + r) * INNER + (h << 6) + 16 * j + s;
      ohi[oo] = hh; olo[oo] = ll;
    }
    if (s == 0) sph[((size_t)bh << 10) + r] = Sco[i];
  }
}

// ---------------- score = sum_h sph / nnz (SCALE already folded into q) ----------------
__global__ __launch_bounds__(256) void score_reduce(const float* __restrict__ sph,
                                                    const float* __restrict__ nnzf,
                                                    float* __restrict__ score) {
  int g = blockIdx.x * 256 + threadIdx.x;
  int b = g >> 10, r = g & 1023;
  float sv = 0.f;
#pragma unroll
  for (int h = 0; h < 8; ++h) sv += sph[(size_t)(((b << 3) + h) << 10) + r];
  score[g] = sv / nnzf[r];
}

// ---------------- per-batch selection of (patches+1) smallest scores ----------------
__global__ __launch_bounds__(256) void select_kernel(const float* __restrict__ score,
                                                     const int* __restrict__ pic_ptr,
                                                     int* __restrict__ asc) {
  int bb = blockIdx.x;
  int t = threadIdx.x;
  int cnt = pic_ptr[0] + 1;
  __shared__ float sv[1024];
  __shared__ float rv[256];
  __shared__ int ri[256];
  for (int i = t; i < 1024; i += 256) sv[i] = score[(size_t)bb * 1024 + i];
  __syncthreads();
  for (int sel = 0; sel < cnt; ++sel) {
    float bv = 3.4e38f; int bi = 1 << 30;
    for (int i = t; i < 1024; i += 256) {
      float v = sv[i];
      if (v < bv) { bv = v; bi = i; }
    }
    rv[t] = bv; ri[t] = bi;
    __syncthreads();
    for (int s2 = 128; s2 > 0; s2 >>= 1) {
      if (t < s2) {
        float ov = rv[t + s2]; int oi = ri[t + s2];
        if (ov < rv[t] || (ov == rv[t] && oi < ri[t])) { rv[t] = ov; ri[t] = oi; }
      }
      __syncthreads();
    }
    if (t == 0) {
      asc[bb * 32 + sel] = ri[0];
      sv[ri[0]] = 3.4e38f;
    }
    __syncthreads();
  }
}

// ---------------- build row-gather map replicating the sequential swap loop ----------------
__global__ __launch_bounds__(256) void build_src(const int* __restrict__ asc,
                                                 const int* __restrict__ pic_ptr,
                                                 int* __restrict__ src) {
  int bi = blockIdx.x;
  int t = threadIdx.x;
  for (int r = t; r < 1024; r += 256) src[bi * 1024 + r] = r;
  __syncthreads();
  if (t == 0) {
    int pic = pic_ptr[0];
    const int* a = &asc[(7 - bi) * 32];   // [::-1] reverses the BATCH axis
    for (int i = 1; i <= pic; ++i) {
      int ti = a[i];
      src[bi * 1024 + i] = ti;
      src[bi * 1024 + ti] = i;
    }
  }
}

// ---------------- out GEMM (split-bf16 MFMA) with fused row gather + bias ----------------
__global__ __launch_bounds__(256) void out_mfma(const unsigned short* __restrict__ ahi,
                                                const unsigned short* __restrict__ alo,
                                                const unsigned short* __restrict__ bhiT,
                                                const unsigned short* __restrict__ bloT,
                                                const float* __restrict__ bias,
                                                const int* __restrict__ src,
                                                float* __restrict__ C) {
  __shared__ __align__(16) unsigned short Ah[128][GPITCH], Al[128][GPITCH];
  __shared__ __align__(16) unsigned short Bh[128][GPITCH], Bl[128][GPITCH];
  int t = threadIdx.x;
  int lane = t & 63, w = t >> 6;
  int wr = w >> 1, wc = w & 1;
  int s = lane & 15, q4 = lane >> 4;
  int r0 = blockIdx.y * 128, c0 = blockIdx.x * 128;
  int bb = r0 >> 10;

  // hoisted gathered A rows for this thread's two staging slots
  int grow[2];
#pragma unroll
  for (int p = 0; p < 2; ++p) {
    int idx = p * 256 + t;
    grow[p] = (bb << 10) + src[r0 + (idx >> 2)];
  }

  floatx4 acc[4][4];
#pragma unroll
  for (int mi = 0; mi < 4; ++mi)
#pragma unroll
    for (int ni = 0; ni < 4; ++ni) { acc[mi][ni][0] = 0.f; acc[mi][ni][1] = 0.f; acc[mi][ni][2] = 0.f; acc[mi][ni][3] = 0.f; }

  for (int kt = 0; kt < INNER; kt += 32) {
    __syncthreads();
#pragma unroll
    for (int p = 0; p < 2; ++p) {
      int idx = p * 256 + t;
      int row = idx >> 2, kc = (idx & 3) * 8;
      *(short8*)&Ah[row][kc] = *(const short8*)&ahi[(size_t)grow[p] * INNER + kt + kc];
      *(short8*)&Al[row][kc] = *(const short8*)&alo[(size_t)grow[p] * INNER + kt + kc];
      *(short8*)&Bh[row][kc] = *(const short8*)&bhiT[(size_t)(c0 + row) * INNER + kt + kc];
      *(short8*)&Bl[row][kc] = *(const short8*)&bloT[(size_t)(c0 + row) * INNER + kt + kc];
    }
    __syncthreads();
    short8 ah[4], al[4], bhf[4], blf[4];
#pragma unroll
    for (int mi = 0; mi < 4; ++mi) {
      ah[mi] = *(const short8*)&Ah[wr * 64 + mi * 16 + s][q4 * 8];
      al[mi] = *(const short8*)&Al[wr * 64 + mi * 16 + s][q4 * 8];
    }
#pragma unroll
    for (int ni = 0; ni < 4; ++ni) {
      bhf[ni] = *(const short8*)&Bh[wc * 64 + ni * 16 + s][q4 * 8];
      blf[ni] = *(const short8*)&Bl[wc * 64 + ni * 16 + s][q4 * 8];
    }
#pragma unroll
    for (int mi = 0; mi < 4; ++mi)
#pragma unroll
      for (int ni = 0; ni < 4; ++ni) {
        acc[mi][ni] = __builtin_amdgcn_mfma_f32_16x16x32_bf16(al[mi], bhf[ni], acc[mi][ni], 0, 0, 0);
        acc[mi][ni] = __builtin_amdgcn_mfma_f32_16x16x32_bf16(ah[mi], blf[ni], acc[mi][ni], 0, 0, 0);
        acc[mi][ni] = __builtin_amdgcn_mfma_f32_16x16x32_bf16(ah[mi], bhf[ni], acc[mi][ni], 0, 0, 0);
      }
  }

#pragma unroll
  for (int ni = 0; ni < 4; ++ni) {
    int Cl = c0 + wc * 64 + ni * 16 + s;
    float bv = bias[Cl];
#pragma unroll
    for (int mi = 0; mi < 4; ++mi)
#pragma unroll
      for (int i = 0; i < 4; ++i) {
        int R = r0 + wr * 64 + mi * 16 + q4 * 4 + i;
        C[(size_t)R * DIM + Cl] = acc[mi][ni][i] + bv;
      }
  }
}

extern "C" void kernel_launch(void* const* d_in, const int* in_sizes, int n_in,
                              void* d_out, int out_size, void* d_ws, size_t ws_size,
                              hipStream_t stream) {
  const float* x      = (const float*)d_in[0];
  const int*   cpmask = (const int*)d_in[1];
  const float* w_qkv  = (const float*)d_in[2];
  const float* w_out  = (const float*)d_in[3];
  const float* b_out  = (const float*)d_in[4];
  const int*   pic    = (const int*)d_in[5];
  float* out = (float*)d_out;

  unsigned short* xhi   = (unsigned short*)d_ws;       // 8192*512 (reused as ohi after qkv)
  unsigned short* xlo   = xhi + 4194304;               // (reused as olo)
  unsigned short* wqhiT = xlo + 4194304;               // 1536*512
  unsigned short* wqloT = wqhiT + 786432;
  unsigned short* wohiT = wqloT + 786432;              // 512*512
  unsigned short* woloT = wohiT + 262144;
  unsigned short* qhi   = woloT + 262144;              // 64*1024*64 each
  unsigned short* qlo   = qhi + 4194304;
  unsigned short* khi   = qlo + 4194304;
  unsigned short* klo   = khi + 4194304;
  unsigned short* vbp   = klo + 4194304;
  float* sph  = (float*)(vbp + 4194304);               // 64*1024
  float* sc   = sph + 65536;                           // 8192
  float* nnzf = sc + 8192;                             // 1024
  int*   asc  = (int*)(nnzf + 1024);                   // 8*32
  int*   src  = asc + 512;                             // 8192
  unsigned long long* Mbits = (unsigned long long*)(src + 8192);  // 1024*16

  unsigned short* ohi = xhi;   // alias: x planes dead after qkv_mfma
  unsigned short* olo = xlo;

  hipLaunchKernelGGL(nnz_kernel,   dim3(1024),    dim3(64),  0, stream, cpmask, nnzf, Mbits);
  hipLaunchKernelGGL(split_kernel, dim3(4096),    dim3(256), 0, stream, x, xhi, xlo, 1048576);
  hipLaunchKernelGGL(tsplit_kernel, dim3(48, 16), dim3(256), 0, stream, w_qkv, DIM, QKV_N, wqhiT, wqloT);
  hipLaunchKernelGGL(tsplit_kernel, dim3(16, 16), dim3(256), 0, stream, w_out, INNER, DIM, wohiT, woloT);
  hipLaunchKernelGGL(qkv_mfma,     dim3(12, 64),  dim3(256), 0, stream, xhi, xlo, wqhiT, wqloT,
                     qhi, qlo, khi, klo, vbp);
  hipLaunchKernelGGL(attn_kernel,  dim3(16, 64),  dim3(256), 0, stream, qhi, qlo, khi, klo, vbp,
                     Mbits, ohi, olo, sph);
  hipLaunchKernelGGL(score_reduce, dim3(32),      dim3(256), 0, stream, sph, nnzf, sc);
  hipLaunchKernelGGL(select_kernel, dim3(8),      dim3(256), 0, stream, sc, pic, asc);
  hipLaunchKernelGGL(build_src,    dim3(8),       dim3(256), 0, stream, asc, pic, src);
  hipLaunchKernelGGL(out_mfma,     dim3(4, 64),   dim3(256), 0, stream, ohi, olo, wohiT, woloT,
                     b_out, src, out);
}

// Round 4
// 258.580 us; speedup vs baseline: 2.5237x; 1.0463x over previous
//
#include <hip/hip_runtime.h>
#include <hip/hip_bf16.h>

#define NN 1024
#define DH 64
#define DIM 512
#define INNER 512
#define QKV_N 1536
#define SCALE 0.125f
#define KPITCH 72   // shorts; attn LDS planes (conflict-optimal for b128 frag reads)

typedef short short8 __attribute__((ext_vector_type(8)));
typedef float floatx4 __attribute__((ext_vector_type(4)));

static __device__ __forceinline__ unsigned short f2bf(float x) {
  __hip_bfloat16 h = __float2bfloat16(x);
  unsigned short u;
  __builtin_memcpy(&u, &h, 2);
  return u;
}
static __device__ __forceinline__ void splitbf(float x, unsigned short& hi, unsigned short& lo) {
  __hip_bfloat16 h = __float2bfloat16(x);
  float hf = __bfloat162float(h);
  __hip_bfloat16 l = __float2bfloat16(x - hf);
  __builtin_memcpy(&hi, &h, 2);
  __builtin_memcpy(&lo, &l, 2);
}
// async global->LDS, 16B per lane; lds dest must be wave-uniform base (HW adds lane*16)
static __device__ __forceinline__ void gll16(const unsigned short* g, unsigned short* l) {
  __builtin_amdgcn_global_load_lds(
      (const __attribute__((address_space(1))) unsigned int*)g,
      (__attribute__((address_space(3))) unsigned int*)l, 16, 0, 0);
}

// ---------------- nnz + 64-col bitmasks per mask row ----------------
__global__ __launch_bounds__(64) void nnz_kernel(const int* __restrict__ mask,
                                                 float* __restrict__ nnzf,
                                                 unsigned long long* __restrict__ Mbits) {
  int row = blockIdx.x;
  int lane = threadIdx.x;
  const int* mrow = mask + (size_t)row * NN;
  int tot = 0;
  for (int mt = 0; mt < 16; ++mt) {
    unsigned long long bits = __ballot(mrow[mt * 64 + lane] != 0);
    if (lane == 0) {
      Mbits[(size_t)row * 16 + mt] = bits;
      tot += __popcll(bits);
    }
  }
  if (lane == 0) nnzf[row] = (float)tot;
}

// ---------------- split fp32 -> hi/lo bf16 ----------------
__global__ __launch_bounds__(256) void split_kernel(const float* __restrict__ in,
                                                    unsigned short* __restrict__ hi,
                                                    unsigned short* __restrict__ lo,
                                                    int n4) {
  int i = blockIdx.x * 256 + threadIdx.x;
  if (i >= n4) return;
  float4 v = ((const float4*)in)[i];
  ushort4 h, l;
  splitbf(v.x, h.x, l.x);
  splitbf(v.y, h.y, l.y);
  splitbf(v.z, h.z, l.z);
  splitbf(v.w, h.w, l.w);
  ((ushort4*)hi)[i] = h;
  ((ushort4*)lo)[i] = l;
}

// ---------------- transpose + split: in [K][N] fp32 -> hiT/loT [N][K] bf16 ----------------
__global__ __launch_bounds__(256) void tsplit_kernel(const float* __restrict__ in, int K, int N,
                                                     unsigned short* __restrict__ hiT,
                                                     unsigned short* __restrict__ loT) {
  __shared__ float tile[32][33];
  int n0 = blockIdx.x * 32, k0 = blockIdx.y * 32;
  int t = threadIdx.x;
  int tn = t & 31, tk = t >> 5;
#pragma unroll
  for (int i = 0; i < 32; i += 8)
    tile[tk + i][tn] = in[(size_t)(k0 + tk + i) * N + n0 + tn];
  __syncthreads();
#pragma unroll
  for (int i = 0; i < 32; i += 8) {
    int n = tk + i;
    float v = tile[tn][n];
    unsigned short h, l;
    splitbf(v, h, l);
    hiT[(size_t)(n0 + n) * K + k0 + tn] = h;
    loT[(size_t)(n0 + n) * K + k0 + tn] = l;
  }
}

// ---------------- QKV GEMM (split-bf16 MFMA, global_load_lds staging) ----------------
__global__ __launch_bounds__(256) void qkv_mfma(const unsigned short* __restrict__ xhi,
                                                const unsigned short* __restrict__ xlo,
                                                const unsigned short* __restrict__ bhiT,
                                                const unsigned short* __restrict__ bloT,
                                                unsigned short* __restrict__ qhi,
                                                unsigned short* __restrict__ qlo,
                                                unsigned short* __restrict__ khi,
                                                unsigned short* __restrict__ klo,
                                                unsigned short* __restrict__ vb) {
  // unpadded [128][32] shorts per plane: lane-contiguous for global_load_lds,
  // 64B pitch -> b128 frag reads spread over all 32 banks
  __shared__ __align__(16) unsigned short Ah[128 * 32], Al[128 * 32];
  __shared__ __align__(16) unsigned short Bh[128 * 32], Bl[128 * 32];
  int t = threadIdx.x;
  int lane = t & 63, w = t >> 6;
  int wr = w >> 1, wc = w & 1;
  int s = lane & 15, q4 = lane >> 4;
  int r0 = blockIdx.y * 128, c0 = blockIdx.x * 128;
  int kcol = (lane & 3) * 8;
  int rA = lane >> 2;        // 0..15 within chunk

  floatx4 acc[4][4];
#pragma unroll
  for (int mi = 0; mi < 4; ++mi)
#pragma unroll
    for (int ni = 0; ni < 4; ++ni) { acc[mi][ni][0] = 0.f; acc[mi][ni][1] = 0.f; acc[mi][ni][2] = 0.f; acc[mi][ni][3] = 0.f; }

  for (int kt = 0; kt < DIM; kt += 32) {
    __syncthreads();
#pragma unroll
    for (int c = 0; c < 2; ++c) {
      int chunk = w * 2 + c;
      int row = chunk * 16 + rA;
      int lo_off = chunk * 512;                 // shorts; wave-uniform
      gll16(&xhi[(size_t)(r0 + row) * DIM + kt + kcol], &Ah[lo_off]);
      gll16(&xlo[(size_t)(r0 + row) * DIM + kt + kcol], &Al[lo_off]);
      gll16(&bhiT[(size_t)(c0 + row) * DIM + kt + kcol], &Bh[lo_off]);
      gll16(&bloT[(size_t)(c0 + row) * DIM + kt + kcol], &Bl[lo_off]);
    }
    __syncthreads();
    short8 ah[4], al[4], bhf[4], blf[4];
#pragma unroll
    for (int mi = 0; mi < 4; ++mi) {
      ah[mi] = *(const short8*)&Ah[(wr * 64 + mi * 16 + s) * 32 + q4 * 8];
      al[mi] = *(const short8*)&Al[(wr * 64 + mi * 16 + s) * 32 + q4 * 8];
    }
#pragma unroll
    for (int ni = 0; ni < 4; ++ni) {
      bhf[ni] = *(const short8*)&Bh[(wc * 64 + ni * 16 + s) * 32 + q4 * 8];
      blf[ni] = *(const short8*)&Bl[(wc * 64 + ni * 16 + s) * 32 + q4 * 8];
    }
#pragma unroll
    for (int mi = 0; mi < 4; ++mi)
#pragma unroll
      for (int ni = 0; ni < 4; ++ni) {
        acc[mi][ni] = __builtin_amdgcn_mfma_f32_16x16x32_bf16(al[mi], bhf[ni], acc[mi][ni], 0, 0, 0);
        acc[mi][ni] = __builtin_amdgcn_mfma_f32_16x16x32_bf16(ah[mi], blf[ni], acc[mi][ni], 0, 0, 0);
        acc[mi][ni] = __builtin_amdgcn_mfma_f32_16x16x32_bf16(ah[mi], bhf[ni], acc[mi][ni], 0, 0, 0);
      }
  }

  int which = c0 >> 9;   // 0=q, 1=k, 2=v
#pragma unroll
  for (int mi = 0; mi < 4; ++mi)
#pragma unroll
    for (int ni = 0; ni < 4; ++ni) {
      int Cl = c0 + wc * 64 + ni * 16 + s;
      int cc = Cl & 511, h = cc >> 6, d = cc & 63;
#pragma unroll
      for (int i = 0; i < 4; ++i) {
        int R = r0 + wr * 64 + mi * 16 + q4 * 4 + i;
        int b = R >> 10, n = R & 1023;
        size_t o = (size_t)((((b << 3) + h) << 10) + n) * DH + d;
        float v = acc[mi][ni][i];
        if (which == 0) {
          unsigned short hh, ll;
          splitbf(SCALE * v, hh, ll);   // fold softmax scale into q (exact pow2)
          qhi[o] = hh; qlo[o] = ll;
        } else if (which == 1) {
          unsigned short hh, ll;
          splitbf(v, hh, ll);
          khi[o] = hh; klo[o] = ll;
        } else {
          vb[o] = f2bf(v);
        }
      }
    }
}

// ---------------- V transpose: [bh][n][d] bf16 -> [bh][d][n] ----------------
__global__ __launch_bounds__(256) void vtrans(const unsigned short* __restrict__ vb,
                                              unsigned short* __restrict__ vT) {
  int bh = blockIdx.y, nt = blockIdx.x;
  __shared__ __align__(16) unsigned short T[64][KPITCH];
  int t = threadIdx.x;
  {
    int n = t >> 2, d0 = (t & 3) * 16;
    const unsigned short* src = &vb[((size_t)bh * NN + nt * 64 + n) * DH + d0];
    *(short8*)&T[n][d0] = *(const short8*)&src[0];
    *(short8*)&T[n][d0 + 8] = *(const short8*)&src[8];
  }
  __syncthreads();
  {
    int d = t >> 2, n0 = (t & 3) * 16;
    short8 o0, o1;
#pragma unroll
    for (int j = 0; j < 8; ++j) {
      o0[j] = (short)T[n0 + j][d];
      o1[j] = (short)T[n0 + 8 + j][d];
    }
    unsigned short* dst = &vT[((size_t)bh * DH + d) * NN + nt * 64 + n0];
    *(short8*)&dst[0] = o0;
    *(short8*)&dst[8] = o1;
  }
}

// ---------------- MFMA flash attention (split-bf16 QK^T, bf16 PV, pre-transposed V) ----------------
__global__ __launch_bounds__(256, 4) void attn_kernel(const unsigned short* __restrict__ qhi,
                                                      const unsigned short* __restrict__ qlo,
                                                      const unsigned short* __restrict__ khi,
                                                      const unsigned short* __restrict__ klo,
                                                      const unsigned short* __restrict__ vT,
                                                      const unsigned long long* __restrict__ Mbits,
                                                      unsigned short* __restrict__ ohi,
                                                      unsigned short* __restrict__ olo,
                                                      float* __restrict__ sph) {
  // XCD-affine swizzle: all 16 rb-blocks of one bh share (linear % 8) -> same XCD L2
  int l = blockIdx.y * 16 + blockIdx.x;
  int k = l >> 3;
  int rb = k & 15;
  int bh = (l & 7) + 8 * (k >> 4);
  int b = bh >> 3, h = bh & 7;
  int row0 = rb * 64;
  int t = threadIdx.x;
  int lane = t & 63, w = t >> 6;
  int q4 = lane >> 4, s = lane & 15;
  int gr = 16 * w + s;

  __shared__ __align__(16) unsigned short Khs[64][KPITCH], Kls[64][KPITCH];
  __shared__ __align__(16) unsigned short Vts[64][KPITCH];
  __shared__ __align__(16) unsigned short Pss[64][KPITCH];
  __shared__ unsigned long long Mb[64];

  // Q fragments: direct global->register (pre-scaled, pre-split)
  short8 aqh[2], aql[2];
  {
    size_t qb0 = ((size_t)bh * NN + row0 + gr) * DH;
#pragma unroll
    for (int ks = 0; ks < 2; ++ks) {
      aqh[ks] = *(const short8*)&qhi[qb0 + ks * 32 + q4 * 8];
      aql[ks] = *(const short8*)&qlo[qb0 + ks * 32 + q4 * 8];
    }
  }

  floatx4 Oacc[4];
  float Lacc[4], Sco[4];
#pragma unroll
  for (int j = 0; j < 4; ++j) { Oacc[j][0] = 0.f; Oacc[j][1] = 0.f; Oacc[j][2] = 0.f; Oacc[j][3] = 0.f; }
#pragma unroll
  for (int i = 0; i < 4; ++i) { Lacc[i] = 0.f; Sco[i] = 0.f; }

  for (int mt = 0; mt < 16; ++mt) {
    int m0 = mt * 64;
    __syncthreads();
    // ---- stage K hi/lo + V^T (all pure b128 copies) + mask bits ----
#pragma unroll
    for (int p = 0; p < 2; ++p) {
      int idx = p * 256 + t;
      int n = idx >> 3, c8 = (idx & 7) * 8;
      size_t g = ((size_t)bh * NN + m0 + n) * DH + c8;
      *(short8*)&Khs[n][c8] = *(const short8*)&khi[g];
      *(short8*)&Kls[n][c8] = *(const short8*)&klo[g];
      // V^T tile: rows = d, cols = m
      *(short8*)&Vts[n][c8] = *(const short8*)&vT[((size_t)bh * DH + n) * NN + m0 + c8];
    }
    if (t < 64) Mb[t] = Mbits[(size_t)(row0 + t) * 16 + mt];
    __syncthreads();

    // ---- S = Q K^T (3-MFMA split; logits pre-scaled) ----
    floatx4 Sf[4];
#pragma unroll
    for (int j = 0; j < 4; ++j) { Sf[j][0] = 0.f; Sf[j][1] = 0.f; Sf[j][2] = 0.f; Sf[j][3] = 0.f; }
#pragma unroll
    for (int ks = 0; ks < 2; ++ks) {
      int d0 = ks * 32 + q4 * 8;
#pragma unroll
      for (int j = 0; j < 4; ++j) {
        short8 kh8 = *(const short8*)&Khs[16 * j + s][d0];
        short8 kl8 = *(const short8*)&Kls[16 * j + s][d0];
        Sf[j] = __builtin_amdgcn_mfma_f32_16x16x32_bf16(aql[ks], kh8, Sf[j], 0, 0, 0);
        Sf[j] = __builtin_amdgcn_mfma_f32_16x16x32_bf16(aqh[ks], kl8, Sf[j], 0, 0, 0);
        Sf[j] = __builtin_amdgcn_mfma_f32_16x16x32_bf16(aqh[ks], kh8, Sf[j], 0, 0, 0);
      }
    }

    // ---- softmax weights + deferred per-lane L/S partials ----
    unsigned long long mb[4];
#pragma unroll
    for (int i = 0; i < 4; ++i) mb[i] = Mb[16 * w + 4 * q4 + i];
    unsigned short pw[4][4];
#pragma unroll
    for (int j = 0; j < 4; ++j) {
#pragma unroll
      for (int i = 0; i < 4; ++i) {
        float sv = Sf[j][i];
        float mf = ((mb[i] >> (16 * j + s)) & 1ULL) ? 1.0f : 0.0f;
        Sco[i] += fabsf(sv) * mf;
        float p = __expf(sv * mf);
        Lacc[i] += p;
        pw[i][j] = f2bf(p);
      }
    }

    // ---- P: C-layout -> A-layout via intra-wave LDS round-trip ----
#pragma unroll
    for (int i = 0; i < 4; ++i)
#pragma unroll
      for (int j = 0; j < 4; ++j) Pss[16 * w + 4 * q4 + i][16 * j + s] = pw[i][j];

    // ---- O += P V ----
#pragma unroll
    for (int ks = 0; ks < 2; ++ks) {
      int mm0 = ks * 32 + q4 * 8;
      short8 ap = *(const short8*)&Pss[gr][mm0];
#pragma unroll
      for (int j = 0; j < 4; ++j) {
        short8 bv = *(const short8*)&Vts[16 * j + s][mm0];
        Oacc[j] = __builtin_amdgcn_mfma_f32_16x16x32_bf16(ap, bv, Oacc[j], 0, 0, 0);
      }
    }
  }

  // ---- final cross-lane reduction + epilogue ----
#pragma unroll
  for (int off = 1; off < 16; off <<= 1) {
#pragma unroll
    for (int i = 0; i < 4; ++i) {
      Lacc[i] += __shfl_xor(Lacc[i], off, 16);
      Sco[i] += __shfl_xor(Sco[i], off, 16);
    }
  }
#pragma unroll
  for (int i = 0; i < 4; ++i) {
    int r = row0 + 16 * w + 4 * q4 + i;
    float iv = 1.0f / Lacc[i];
#pragma unroll
    for (int j = 0; j < 4; ++j) {
      float o = Oacc[j][i] * iv;
      unsigned short hh, ll;
      splitbf(o, hh, ll);
      size_t oo = (size_t)((b << 10) + r) * INNER + (h << 6) + 16 * j + s;
      ohi[oo] = hh; olo[oo] = ll;
    }
    if (s == 0) sph[((size_t)bh << 10) + r] = Sco[i];
  }
}

// ---------------- fused score + per-batch selection of (patches+1) smallest ----------------
__global__ __launch_bounds__(256) void score_select(const float* __restrict__ sph,
                                                    const float* __restrict__ nnzf,
                                                    const int* __restrict__ pic_ptr,
                                                    int* __restrict__ asc) {
  int bb = blockIdx.x;
  int t = threadIdx.x;
  int cnt = pic_ptr[0] + 1;
  float v[4];
#pragma unroll
  for (int i = 0; i < 4; ++i) {
    int r = t + 256 * i;
    float sv = 0.f;
#pragma unroll
    for (int h = 0; h < 8; ++h) sv += sph[(size_t)(((bb << 3) + h) << 10) + r];
    v[i] = sv / nnzf[r];
  }
  __shared__ float wv[4];
  __shared__ int wi[4];
  __shared__ int bsel;
  for (int sel = 0; sel < cnt; ++sel) {
    float bv = v[0];
    int bi = t;
#pragma unroll
    for (int i = 1; i < 4; ++i) {
      if (v[i] < bv) { bv = v[i]; bi = t + 256 * i; }   // ascending i -> smallest idx on ties
    }
#pragma unroll
    for (int off = 1; off < 64; off <<= 1) {
      float ov = __shfl_xor(bv, off, 64);
      int oi = __shfl_xor(bi, off, 64);
      if (ov < bv || (ov == bv && oi < bi)) { bv = ov; bi = oi; }
    }
    if ((t & 63) == 0) { wv[t >> 6] = bv; wi[t >> 6] = bi; }
    __syncthreads();
    if (t == 0) {
      float B = wv[0]; int I = wi[0];
#pragma unroll
      for (int q = 1; q < 4; ++q) {
        if (wv[q] < B || (wv[q] == B && wi[q] < I)) { B = wv[q]; I = wi[q]; }
      }
      bsel = I;
      asc[bb * 32 + sel] = I;
    }
    __syncthreads();
    int wloc = bsel - t;
    if (wloc >= 0 && (wloc & 255) == 0 && wloc < 1024) v[wloc >> 8] = 3.4e38f;
    __syncthreads();
  }
}

// ---------------- build row-gather map replicating the sequential swap loop ----------------
__global__ __launch_bounds__(256) void build_src(const int* __restrict__ asc,
                                                 const int* __restrict__ pic_ptr,
                                                 int* __restrict__ src) {
  int bi = blockIdx.x;
  int t = threadIdx.x;
  for (int r = t; r < 1024; r += 256) src[bi * 1024 + r] = r;
  __syncthreads();
  if (t == 0) {
    int pic = pic_ptr[0];
    const int* a = &asc[(7 - bi) * 32];   // [::-1] reverses the BATCH axis
    for (int i = 1; i <= pic; ++i) {
      int ti = a[i];
      src[bi * 1024 + i] = ti;
      src[bi * 1024 + ti] = i;
    }
  }
}

// ---------------- out GEMM (split-bf16 MFMA, global_load_lds, fused row gather + bias) ----------------
__global__ __launch_bounds__(256) void out_mfma(const unsigned short* __restrict__ ahi,
                                                const unsigned short* __restrict__ alo,
                                                const unsigned short* __restrict__ bhiT,
                                                const unsigned short* __restrict__ bloT,
                                                const float* __restrict__ bias,
                                                const int* __restrict__ src,
                                                float* __restrict__ C) {
  __shared__ __align__(16) unsigned short Ah[128 * 32], Al[128 * 32];
  __shared__ __align__(16) unsigned short Bh[128 * 32], Bl[128 * 32];
  int t = threadIdx.x;
  int lane = t & 63, w = t >> 6;
  int wr = w >> 1, wc = w & 1;
  int s = lane & 15, q4 = lane >> 4;
  int r0 = blockIdx.y * 128, c0 = blockIdx.x * 128;
  int bb = r0 >> 10;
  int kcol = (lane & 3) * 8;
  int rA = lane >> 2;

  int grow[2];
#pragma unroll
  for (int c = 0; c < 2; ++c) {
    int row = (w * 2 + c) * 16 + rA;
    grow[c] = (bb << 10) + src[r0 + row];
  }

  floatx4 acc[4][4];
#pragma unroll
  for (int mi = 0; mi < 4; ++mi)
#pragma unroll
    for (int ni = 0; ni < 4; ++ni) { acc[mi][ni][0] = 0.f; acc[mi][ni][1] = 0.f; acc[mi][ni][2] = 0.f; acc[mi][ni][3] = 0.f; }

  for (int kt = 0; kt < INNER; kt += 32) {
    __syncthreads();
#pragma unroll
    for (int c = 0; c < 2; ++c) {
      int chunk = w * 2 + c;
      int row = chunk * 16 + rA;
      int lo_off = chunk * 512;
      gll16(&ahi[(size_t)grow[c] * INNER + kt + kcol], &Ah[lo_off]);
      gll16(&alo[(size_t)grow[c] * INNER + kt + kcol], &Al[lo_off]);
      gll16(&bhiT[(size_t)(c0 + row) * INNER + kt + kcol], &Bh[lo_off]);
      gll16(&bloT[(size_t)(c0 + row) * INNER + kt + kcol], &Bl[lo_off]);
    }
    __syncthreads();
    short8 ah[4], al[4], bhf[4], blf[4];
#pragma unroll
    for (int mi = 0; mi < 4; ++mi) {
      ah[mi] = *(const short8*)&Ah[(wr * 64 + mi * 16 + s) * 32 + q4 * 8];
      al[mi] = *(const short8*)&Al[(wr * 64 + mi * 16 + s) * 32 + q4 * 8];
    }
#pragma unroll
    for (int ni = 0; ni < 4; ++ni) {
      bhf[ni] = *(const short8*)&Bh[(wc * 64 + ni * 16 + s) * 32 + q4 * 8];
      blf[ni] = *(const short8*)&Bl[(wc * 64 + ni * 16 + s) * 32 + q4 * 8];
    }
#pragma unroll
    for (int mi = 0; mi < 4; ++mi)
#pragma unroll
      for (int ni = 0; ni < 4; ++ni) {
        acc[mi][ni] = __builtin_amdgcn_mfma_f32_16x16x32_bf16(al[mi], bhf[ni], acc[mi][ni], 0, 0, 0);
        acc[mi][ni] = __builtin_amdgcn_mfma_f32_16x16x32_bf16(ah[mi], blf[ni], acc[mi][ni], 0, 0, 0);
        acc[mi][ni] = __builtin_amdgcn_mfma_f32_16x16x32_bf16(ah[mi], bhf[ni], acc[mi][ni], 0, 0, 0);
      }
  }

#pragma unroll
  for (int ni = 0; ni < 4; ++ni) {
    int Cl = c0 + wc * 64 + ni * 16 + s;
    float bv = bias[Cl];
#pragma unroll
    for (int mi = 0; mi < 4; ++mi)
#pragma unroll
      for (int i = 0; i < 4; ++i) {
        int R = r0 + wr * 64 + mi * 16 + q4 * 4 + i;
        C[(size_t)R * DIM + Cl] = acc[mi][ni][i] + bv;
      }
  }
}

extern "C" void kernel_launch(void* const* d_in, const int* in_sizes, int n_in,
                              void* d_out, int out_size, void* d_ws, size_t ws_size,
                              hipStream_t stream) {
  const float* x      = (const float*)d_in[0];
  const int*   cpmask = (const int*)d_in[1];
  const float* w_qkv  = (const float*)d_in[2];
  const float* w_out  = (const float*)d_in[3];
  const float* b_out  = (const float*)d_in[4];
  const int*   pic    = (const int*)d_in[5];
  float* out = (float*)d_out;

  unsigned short* xhi   = (unsigned short*)d_ws;       // 8192*512 (reused as ohi after qkv)
  unsigned short* xlo   = xhi + 4194304;               // (reused as olo)
  unsigned short* wqhiT = xlo + 4194304;               // 1536*512
  unsigned short* wqloT = wqhiT + 786432;
  unsigned short* wohiT = wqloT + 786432;              // 512*512
  unsigned short* woloT = wohiT + 262144;
  unsigned short* qhi   = woloT + 262144;              // 64*1024*64 each
  unsigned short* qlo   = qhi + 4194304;
  unsigned short* khi   = qlo + 4194304;
  unsigned short* klo   = khi + 4194304;
  unsigned short* vbp   = klo + 4194304;
  float* sph  = (float*)(vbp + 4194304);               // 64*1024
  float* sc   = sph + 65536;                           // (unused slot kept for layout stability)
  float* nnzf = sc + 8192;                             // 1024
  int*   asc  = (int*)(nnzf + 1024);                   // 8*32
  int*   src  = asc + 512;                             // 8192
  unsigned long long* Mbits = (unsigned long long*)(src + 8192);  // 1024*16
  unsigned short* vTp = (unsigned short*)(Mbits + 16384);         // 64*64*1024

  unsigned short* ohi = xhi;   // alias: x planes dead after qkv_mfma
  unsigned short* olo = xlo;

  hipLaunchKernelGGL(nnz_kernel,    dim3(1024),    dim3(64),  0, stream, cpmask, nnzf, Mbits);
  hipLaunchKernelGGL(split_kernel,  dim3(4096),    dim3(256), 0, stream, x, xhi, xlo, 1048576);
  hipLaunchKernelGGL(tsplit_kernel, dim3(48, 16),  dim3(256), 0, stream, w_qkv, DIM, QKV_N, wqhiT, wqloT);
  hipLaunchKernelGGL(tsplit_kernel, dim3(16, 16),  dim3(256), 0, stream, w_out, INNER, DIM, wohiT, woloT);
  hipLaunchKernelGGL(qkv_mfma,      dim3(12, 64),  dim3(256), 0, stream, xhi, xlo, wqhiT, wqloT,
                     qhi, qlo, khi, klo, vbp);
  hipLaunchKernelGGL(vtrans,        dim3(16, 64),  dim3(256), 0, stream, vbp, vTp);
  hipLaunchKernelGGL(attn_kernel,   dim3(16, 64),  dim3(256), 0, stream, qhi, qlo, khi, klo, vTp,
                     Mbits, ohi, olo, sph);
  hipLaunchKernelGGL(score_select,  dim3(8),       dim3(256), 0, stream, sph, nnzf, pic, asc);
  hipLaunchKernelGGL(build_src,     dim3(8),       dim3(256), 0, stream, asc, pic, src);
  hipLaunchKernelGGL(out_mfma,      dim3(4, 64),   dim3(256), 0, stream, ohi, olo, wohiT, woloT,
                     b_out, src, out);
}

// Round 5
// 226.541 us; speedup vs baseline: 2.8806x; 1.1414x over previous
//
#include <hip/hip_runtime.h>
#include <hip/hip_bf16.h>

#define NN 1024
#define DH 64
#define DIM 512
#define INNER 512
#define QKV_N 1536
#define SCALE 0.125f
#define PPITCH 72     // shorts; Ps plane (144B = 9*16B: b128-aligned)

typedef short short8 __attribute__((ext_vector_type(8)));
typedef float floatx4 __attribute__((ext_vector_type(4)));

static __device__ __forceinline__ unsigned short f2bf(float x) {
  __hip_bfloat16 h = __float2bfloat16(x);
  unsigned short u;
  __builtin_memcpy(&u, &h, 2);
  return u;
}
static __device__ __forceinline__ void splitbf(float x, unsigned short& hi, unsigned short& lo) {
  __hip_bfloat16 h = __float2bfloat16(x);
  float hf = __bfloat162float(h);
  __hip_bfloat16 l = __float2bfloat16(x - hf);
  __builtin_memcpy(&hi, &h, 2);
  __builtin_memcpy(&lo, &l, 2);
}
static __device__ __forceinline__ void gll16(const unsigned short* g, unsigned short* l) {
  __builtin_amdgcn_global_load_lds(
      (const __attribute__((address_space(1))) unsigned int*)g,
      (__attribute__((address_space(3))) unsigned int*)l, 16, 0, 0);
}

// ---------------- nnz + 64-col bitmasks per mask row (Mbits layout: [mt][row]) ----------------
__global__ __launch_bounds__(64) void nnz_kernel(const int* __restrict__ mask,
                                                 float* __restrict__ nnzf,
                                                 unsigned long long* __restrict__ Mbits) {
  int row = blockIdx.x;
  int lane = threadIdx.x;
  const int* mrow = mask + (size_t)row * NN;
  int tot = 0;
  for (int mt = 0; mt < 16; ++mt) {
    unsigned long long bits = __ballot(mrow[mt * 64 + lane] != 0);
    if (lane == 0) {
      Mbits[(size_t)mt * NN + row] = bits;
      tot += __popcll(bits);
    }
  }
  if (lane == 0) nnzf[row] = (float)tot;
}

// ---------------- split fp32 -> hi/lo bf16 ----------------
__global__ __launch_bounds__(256) void split_kernel(const float* __restrict__ in,
                                                    unsigned short* __restrict__ hi,
                                                    unsigned short* __restrict__ lo,
                                                    int n4) {
  int i = blockIdx.x * 256 + threadIdx.x;
  if (i >= n4) return;
  float4 v = ((const float4*)in)[i];
  ushort4 h, l;
  splitbf(v.x, h.x, l.x);
  splitbf(v.y, h.y, l.y);
  splitbf(v.z, h.z, l.z);
  splitbf(v.w, h.w, l.w);
  ((ushort4*)hi)[i] = h;
  ((ushort4*)lo)[i] = l;
}

// ---------------- transpose + split: in [K][N] fp32 -> hiT/loT [N][K] bf16 ----------------
__global__ __launch_bounds__(256) void tsplit_kernel(const float* __restrict__ in, int K, int N,
                                                     unsigned short* __restrict__ hiT,
                                                     unsigned short* __restrict__ loT) {
  __shared__ float tile[32][33];
  int n0 = blockIdx.x * 32, k0 = blockIdx.y * 32;
  int t = threadIdx.x;
  int tn = t & 31, tk = t >> 5;
#pragma unroll
  for (int i = 0; i < 32; i += 8)
    tile[tk + i][tn] = in[(size_t)(k0 + tk + i) * N + n0 + tn];
  __syncthreads();
#pragma unroll
  for (int i = 0; i < 32; i += 8) {
    int n = tk + i;
    float v = tile[tn][n];
    unsigned short h, l;
    splitbf(v, h, l);
    hiT[(size_t)(n0 + n) * K + k0 + tn] = h;
    loT[(size_t)(n0 + n) * K + k0 + tn] = l;
  }
}

// ---------------- QKV GEMM: BK=64, swizzled full-line gll16 staging, LDS-relayout epilogue ----------------
// grid 768 1-D: by = l&63 (row tile), bx = l>>6 (col tile). Same-A blocks share XCD (%8).
__global__ __launch_bounds__(256) void qkv_mfma(const unsigned short* __restrict__ xhi,
                                                const unsigned short* __restrict__ xlo,
                                                const unsigned short* __restrict__ bhiT,
                                                const unsigned short* __restrict__ bloT,
                                                unsigned short* __restrict__ qhi,
                                                unsigned short* __restrict__ qlo,
                                                unsigned short* __restrict__ khi,
                                                unsigned short* __restrict__ klo,
                                                unsigned short* __restrict__ vT) {
  // union: 4 bf16 planes [128][64] (65536 B)  |  fp32 C tile [128][132] (67584 B)
  __shared__ __align__(16) unsigned char smemQ[67584];
  unsigned short* planeS = (unsigned short*)smemQ;
  float* ct = (float*)smemQ;

  int l = blockIdx.x;
  int by = l & 63, bx = l >> 6;
  int r0 = by * 128, c0 = bx * 128;
  int which = c0 >> 9;                 // 0=q, 1=k, 2=v
  bool split3 = (which != 2);          // v: hi*hi only (rounded to bf16 anyway)
  int t = threadIdx.x;
  int lane = t & 63, w = t >> 6;
  int wr = w >> 1, wc = w & 1;
  int s = lane & 15, q4 = lane >> 4;
  int sx7 = s & 7;
  int r8 = lane >> 3, j7 = lane & 7;
  int colsw = ((j7 ^ r8) << 3);        // chunk swizzle keyed to LDS row&7 (= r8)

  // wave w stages plane w
  const unsigned short* gsrc;
  int tb;
  if (w == 0) { gsrc = xhi; tb = r0; }
  else if (w == 1) { gsrc = xlo; tb = r0; }
  else if (w == 2) { gsrc = bhiT; tb = c0; }
  else { gsrc = bloT; tb = c0; }
  unsigned short* lp = planeS + w * 8192;
  const unsigned short* gp = gsrc + (size_t)(tb + r8) * DIM + colsw;
  bool doStage = split3 || (w == 0) || (w == 2);

  const unsigned short* Ah = planeS;
  const unsigned short* Al = planeS + 8192;
  const unsigned short* Bh = planeS + 16384;
  const unsigned short* Bl = planeS + 24576;

  floatx4 acc[4][4];
#pragma unroll
  for (int mi = 0; mi < 4; ++mi)
#pragma unroll
    for (int ni = 0; ni < 4; ++ni) { acc[mi][ni][0] = 0.f; acc[mi][ni][1] = 0.f; acc[mi][ni][2] = 0.f; acc[mi][ni][3] = 0.f; }

  for (int kt = 0; kt < DIM; kt += 64) {
    __syncthreads();
    if (doStage) {
#pragma unroll
      for (int ii = 0; ii < 16; ++ii)
        gll16(gp + (size_t)ii * 8 * DIM + kt, lp + ii * 512);
    }
    __syncthreads();
#pragma unroll
    for (int ks2 = 0; ks2 < 2; ++ks2) {
      int pc = ((ks2 * 4 + q4) ^ sx7) << 3;
      short8 ah[4], al[4], bhf[4], blf[4];
#pragma unroll
      for (int mi = 0; mi < 4; ++mi) {
        int ra = (wr * 64 + mi * 16 + s) * 64 + pc;
        ah[mi] = *(const short8*)&Ah[ra];
        if (split3) al[mi] = *(const short8*)&Al[ra];
      }
#pragma unroll
      for (int ni = 0; ni < 4; ++ni) {
        int rb = (wc * 64 + ni * 16 + s) * 64 + pc;
        bhf[ni] = *(const short8*)&Bh[rb];
        if (split3) blf[ni] = *(const short8*)&Bl[rb];
      }
#pragma unroll
      for (int mi = 0; mi < 4; ++mi)
#pragma unroll
        for (int ni = 0; ni < 4; ++ni) {
          if (split3) {
            acc[mi][ni] = __builtin_amdgcn_mfma_f32_16x16x32_bf16(al[mi], bhf[ni], acc[mi][ni], 0, 0, 0);
            acc[mi][ni] = __builtin_amdgcn_mfma_f32_16x16x32_bf16(ah[mi], blf[ni], acc[mi][ni], 0, 0, 0);
          }
          acc[mi][ni] = __builtin_amdgcn_mfma_f32_16x16x32_bf16(ah[mi], bhf[ni], acc[mi][ni], 0, 0, 0);
        }
    }
  }

  // ---- epilogue: fp32 LDS relayout -> full-line split-bf16 stores ----
  __syncthreads();
  if (which != 2) {
    float sc = (which == 0) ? SCALE : 1.0f;
#pragma unroll
    for (int mi = 0; mi < 4; ++mi)
#pragma unroll
      for (int ni = 0; ni < 4; ++ni)
#pragma unroll
        for (int i = 0; i < 4; ++i)
          ct[(wr * 64 + mi * 16 + q4 * 4 + i) * 132 + (wc * 64 + ni * 16 + s)] = acc[mi][ni][i] * sc;
  } else {
#pragma unroll
    for (int mi = 0; mi < 4; ++mi)
#pragma unroll
      for (int ni = 0; ni < 4; ++ni)
#pragma unroll
        for (int i = 0; i < 4; ++i)
          ct[(wc * 64 + ni * 16 + s) * 132 + (wr * 64 + mi * 16 + q4 * 4 + i)] = acc[mi][ni][i];
  }
  __syncthreads();
  if (which != 2) {
    int tr = t >> 1, ch = t & 1;
    int R = r0 + tr, b = R >> 10, n = R & 1023;
    int h0 = ((c0 & 511) >> 6) + ch;
    unsigned short* dhi = (which == 0) ? qhi : khi;
    unsigned short* dlo = (which == 0) ? qlo : klo;
    size_t go = ((size_t)(((b << 3) + h0) << 10) + n) * DH;
#pragma unroll
    for (int u = 0; u < 4; ++u) {
      const float* src = &ct[tr * 132 + ch * 64 + u * 16];
      short8 h8a, h8b, l8a, l8b;
#pragma unroll
      for (int e = 0; e < 8; ++e) {
        unsigned short hh, ll;
        splitbf(src[e], hh, ll);
        h8a[e] = (short)hh; l8a[e] = (short)ll;
        splitbf(src[8 + e], hh, ll);
        h8b[e] = (short)hh; l8b[e] = (short)ll;
      }
      *(short8*)&dhi[go + u * 16] = h8a;
      *(short8*)&dhi[go + u * 16 + 8] = h8b;
      *(short8*)&dlo[go + u * 16] = l8a;
      *(short8*)&dlo[go + u * 16 + 8] = l8b;
    }
  } else {
    int cr = t >> 1, th = t & 1;
    int b = r0 >> 10;
    int hglob = ((c0 & 511) >> 6) + (cr >> 6);
    int d = cr & 63;
    int n0 = (r0 & 1023) + th * 64;
    size_t go = ((size_t)(((b << 3) + hglob) * DH) + d) * NN + n0;
#pragma unroll
    for (int u = 0; u < 4; ++u) {
      const float* src = &ct[cr * 132 + th * 64 + u * 16];
      short8 o0, o1;
#pragma unroll
      for (int e = 0; e < 8; ++e) {
        o0[e] = (short)f2bf(src[e]);
        o1[e] = (short)f2bf(src[8 + e]);
      }
      *(short8*)&vT[go + u * 16] = o0;
      *(short8*)&vT[go + u * 16 + 8] = o1;
    }
  }
}

// ---------------- MFMA flash attention: swizzled gll16 staging, LDS-relayout epilogue ----------------
__global__ __launch_bounds__(256, 4) void attn_kernel(const unsigned short* __restrict__ qhi,
                                                      const unsigned short* __restrict__ qlo,
                                                      const unsigned short* __restrict__ khi,
                                                      const unsigned short* __restrict__ klo,
                                                      const unsigned short* __restrict__ vT,
                                                      const unsigned long long* __restrict__ MbT,
                                                      unsigned short* __restrict__ ohi,
                                                      unsigned short* __restrict__ olo,
                                                      float* __restrict__ sph) {
  // XCD-affine swizzle: all 16 rb-blocks of one bh share (linear % 8)
  int l = blockIdx.y * 16 + blockIdx.x;
  int k = l >> 3;
  int rb = k & 15;
  int bh = (l & 7) + 8 * (k >> 4);
  int b = bh >> 3, h = bh & 7;
  int row0 = rb * 64;
  int t = threadIdx.x;
  int lane = t & 63, w = t >> 6;
  int q4 = lane >> 4, s = lane & 15;
  int sx7 = s & 7;
  int gr = 16 * w + s;
  int r8 = lane >> 3, j7 = lane & 7;
  int colsw = ((j7 ^ r8) << 3);

  __shared__ __align__(16) unsigned short stageS[3 * 4096];  // Khs | Kls | Vts, [64][64] each
  __shared__ __align__(16) unsigned short Ps[64 * PPITCH];
  __shared__ unsigned long long Mb[64];
  unsigned short* Khs = stageS;
  unsigned short* Kls = stageS + 4096;
  unsigned short* Vts = stageS + 8192;
  float* Ofl = (float*)stageS;   // [64][68] fp32, reused after main loop

  // staging source pointers (wave w stages rows 16w..16w+15 of each plane)
  const unsigned short* khp = khi + ((size_t)bh * NN + 16 * w + r8) * DH + colsw;
  const unsigned short* klp = klo + ((size_t)bh * NN + 16 * w + r8) * DH + colsw;
  const unsigned short* vtp = vT + ((size_t)bh * DH + 16 * w + r8) * NN + colsw;

  // Q fragments: direct global->register (pre-scaled, pre-split)
  short8 aqh[2], aql[2];
  {
    size_t qb0 = ((size_t)bh * NN + row0 + gr) * DH;
#pragma unroll
    for (int ks = 0; ks < 2; ++ks) {
      aqh[ks] = *(const short8*)&qhi[qb0 + ks * 32 + q4 * 8];
      aql[ks] = *(const short8*)&qlo[qb0 + ks * 32 + q4 * 8];
    }
  }

  floatx4 Oacc[4];
  float Lacc[4], Sco[4];
#pragma unroll
  for (int j = 0; j < 4; ++j) { Oacc[j][0] = 0.f; Oacc[j][1] = 0.f; Oacc[j][2] = 0.f; Oacc[j][3] = 0.f; }
#pragma unroll
  for (int i = 0; i < 4; ++i) { Lacc[i] = 0.f; Sco[i] = 0.f; }

  for (int mt = 0; mt < 16; ++mt) {
    __syncthreads();
#pragma unroll
    for (int ii = 0; ii < 2; ++ii) {
      int lofs = (16 * w + 8 * ii) * 64;
      gll16(khp + (size_t)mt * 64 * DH + (size_t)ii * 8 * DH, Khs + lofs);
      gll16(klp + (size_t)mt * 64 * DH + (size_t)ii * 8 * DH, Kls + lofs);
      gll16(vtp + (size_t)mt * 64 + (size_t)ii * 8 * NN, Vts + lofs);
    }
    if (t < 64) Mb[t] = MbT[(size_t)mt * NN + row0 + t];
    __syncthreads();

    // ---- S = Q K^T (3-MFMA split; logits pre-scaled) ----
    floatx4 Sf[4];
#pragma unroll
    for (int j = 0; j < 4; ++j) { Sf[j][0] = 0.f; Sf[j][1] = 0.f; Sf[j][2] = 0.f; Sf[j][3] = 0.f; }
#pragma unroll
    for (int ks = 0; ks < 2; ++ks) {
      int pc = ((ks * 4 + q4) ^ sx7) << 3;
#pragma unroll
      for (int j = 0; j < 4; ++j) {
        int rk = (16 * j + s) * 64 + pc;
        short8 kh8 = *(const short8*)&Khs[rk];
        short8 kl8 = *(const short8*)&Kls[rk];
        Sf[j] = __builtin_amdgcn_mfma_f32_16x16x32_bf16(aql[ks], kh8, Sf[j], 0, 0, 0);
        Sf[j] = __builtin_amdgcn_mfma_f32_16x16x32_bf16(aqh[ks], kl8, Sf[j], 0, 0, 0);
        Sf[j] = __builtin_amdgcn_mfma_f32_16x16x32_bf16(aqh[ks], kh8, Sf[j], 0, 0, 0);
      }
    }

    // ---- softmax weights + deferred per-lane L/S partials ----
    unsigned long long mb[4];
#pragma unroll
    for (int i = 0; i < 4; ++i) mb[i] = Mb[16 * w + 4 * q4 + i];
    unsigned short pw[4][4];
#pragma unroll
    for (int j = 0; j < 4; ++j) {
#pragma unroll
      for (int i = 0; i < 4; ++i) {
        float sv = Sf[j][i];
        float mf = ((mb[i] >> (16 * j + s)) & 1ULL) ? 1.0f : 0.0f;
        Sco[i] += fabsf(sv) * mf;
        float p = __expf(sv * mf);
        Lacc[i] += p;
        pw[i][j] = f2bf(p);
      }
    }

    // ---- P: C-layout -> A-layout via intra-wave LDS round-trip ----
#pragma unroll
    for (int i = 0; i < 4; ++i)
#pragma unroll
      for (int j = 0; j < 4; ++j) Ps[(16 * w + 4 * q4 + i) * PPITCH + 16 * j + s] = pw[i][j];

    // ---- O += P V ----
#pragma unroll
    for (int ks = 0; ks < 2; ++ks) {
      int mm0 = ks * 32 + q4 * 8;
      short8 ap = *(const short8*)&Ps[gr * PPITCH + mm0];
      int pc = ((ks * 4 + q4) ^ sx7) << 3;
#pragma unroll
      for (int j = 0; j < 4; ++j) {
        short8 bv = *(const short8*)&Vts[(16 * j + s) * 64 + pc];
        Oacc[j] = __builtin_amdgcn_mfma_f32_16x16x32_bf16(ap, bv, Oacc[j], 0, 0, 0);
      }
    }
  }

  // ---- final cross-lane reduction, sph ----
#pragma unroll
  for (int off = 1; off < 16; off <<= 1) {
#pragma unroll
    for (int i = 0; i < 4; ++i) {
      Lacc[i] += __shfl_xor(Lacc[i], off, 16);
      Sco[i] += __shfl_xor(Sco[i], off, 16);
    }
  }
  if (s == 0) {
#pragma unroll
    for (int i = 0; i < 4; ++i)
      sph[((size_t)bh << 10) + row0 + 16 * w + 4 * q4 + i] = Sco[i];
  }

  // ---- O epilogue: fp32 LDS relayout -> full-line split-bf16 stores ----
  __syncthreads();
#pragma unroll
  for (int i = 0; i < 4; ++i) {
    float iv = 1.0f / Lacc[i];
#pragma unroll
    for (int j = 0; j < 4; ++j)
      Ofl[(16 * w + 4 * q4 + i) * 68 + 16 * j + s] = Oacc[j][i] * iv;
  }
  __syncthreads();
  {
    int tr = t >> 2, dq = t & 3;
    int r = row0 + tr;
    size_t go = ((size_t)((b << 10) + r)) * INNER + (h << 6) + dq * 16;
    const float* src = &Ofl[tr * 68 + dq * 16];
    short8 h8a, h8b, l8a, l8b;
#pragma unroll
    for (int e = 0; e < 8; ++e) {
      unsigned short hh, ll;
      splitbf(src[e], hh, ll);
      h8a[e] = (short)hh; l8a[e] = (short)ll;
      splitbf(src[8 + e], hh, ll);
      h8b[e] = (short)hh; l8b[e] = (short)ll;
    }
    *(short8*)&ohi[go] = h8a;
    *(short8*)&ohi[go + 8] = h8b;
    *(short8*)&olo[go] = l8a;
    *(short8*)&olo[go + 8] = l8b;
  }
}

// ---------------- fused score + per-batch selection of (patches+1) smallest ----------------
__global__ __launch_bounds__(256) void score_select(const float* __restrict__ sph,
                                                    const float* __restrict__ nnzf,
                                                    const int* __restrict__ pic_ptr,
                                                    int* __restrict__ asc) {
  int bb = blockIdx.x;
  int t = threadIdx.x;
  int cnt = pic_ptr[0] + 1;
  float v[4];
#pragma unroll
  for (int i = 0; i < 4; ++i) {
    int r = t + 256 * i;
    float sv = 0.f;
#pragma unroll
    for (int h = 0; h < 8; ++h) sv += sph[(size_t)(((bb << 3) + h) << 10) + r];
    v[i] = sv / nnzf[r];
  }
  __shared__ float wv[4];
  __shared__ int wi[4];
  __shared__ int bsel;
  for (int sel = 0; sel < cnt; ++sel) {
    float bv = v[0];
    int bi = t;
#pragma unroll
    for (int i = 1; i < 4; ++i) {
      if (v[i] < bv) { bv = v[i]; bi = t + 256 * i; }
    }
#pragma unroll
    for (int off = 1; off < 64; off <<= 1) {
      float ov = __shfl_xor(bv, off, 64);
      int oi = __shfl_xor(bi, off, 64);
      if (ov < bv || (ov == bv && oi < bi)) { bv = ov; bi = oi; }
    }
    if ((t & 63) == 0) { wv[t >> 6] = bv; wi[t >> 6] = bi; }
    __syncthreads();
    if (t == 0) {
      float B = wv[0]; int I = wi[0];
#pragma unroll
      for (int q = 1; q < 4; ++q) {
        if (wv[q] < B || (wv[q] == B && wi[q] < I)) { B = wv[q]; I = wi[q]; }
      }
      bsel = I;
      asc[bb * 32 + sel] = I;
    }
    __syncthreads();
    int wloc = bsel - t;
    if (wloc >= 0 && (wloc & 255) == 0 && wloc < 1024) v[wloc >> 8] = 3.4e38f;
    __syncthreads();
  }
}

// ---------------- build row-gather map replicating the sequential swap loop ----------------
__global__ __launch_bounds__(256) void build_src(const int* __restrict__ asc,
                                                 const int* __restrict__ pic_ptr,
                                                 int* __restrict__ src) {
  int bi = blockIdx.x;
  int t = threadIdx.x;
  for (int r = t; r < 1024; r += 256) src[bi * 1024 + r] = r;
  __syncthreads();
  if (t == 0) {
    int pic = pic_ptr[0];
    const int* a = &asc[(7 - bi) * 32];   // [::-1] reverses the BATCH axis
    for (int i = 1; i <= pic; ++i) {
      int ti = a[i];
      src[bi * 1024 + i] = ti;
      src[bi * 1024 + ti] = i;
    }
  }
}

// ---------------- out GEMM: BK=64 swizzled gll16 staging, fused row gather + bias ----------------
// grid 256 1-D: by = l&63 (row tile), bx = l>>6 (col tile)
__global__ __launch_bounds__(256) void out_mfma(const unsigned short* __restrict__ ahi,
                                                const unsigned short* __restrict__ alo,
                                                const unsigned short* __restrict__ bhiT,
                                                const unsigned short* __restrict__ bloT,
                                                const float* __restrict__ bias,
                                                const int* __restrict__ src,
                                                float* __restrict__ C) {
  __shared__ __align__(16) unsigned short planeS[4 * 8192];
  int l = blockIdx.x;
  int by = l & 63, bx = l >> 6;
  int r0 = by * 128, c0 = bx * 128;
  int t = threadIdx.x;
  int lane = t & 63, w = t >> 6;
  int wr = w >> 1, wc = w & 1;
  int s = lane & 15, q4 = lane >> 4;
  int sx7 = s & 7;
  int r8 = lane >> 3, j7 = lane & 7;
  int colsw = ((j7 ^ r8) << 3);
  int bb1024 = (r0 >> 10) << 10;

  // per-lane gathered A rows (waves 0/1 only)
  int srcrow[16];
  if (w < 2) {
#pragma unroll
    for (int ii = 0; ii < 16; ++ii) srcrow[ii] = src[r0 + ii * 8 + r8];
  }
  const unsigned short* gsrc = (w == 0) ? ahi : (w == 1) ? alo : (w == 2) ? bhiT : bloT;
  unsigned short* lp = planeS + w * 8192;

  const unsigned short* Ah = planeS;
  const unsigned short* Al = planeS + 8192;
  const unsigned short* Bh = planeS + 16384;
  const unsigned short* Bl = planeS + 24576;

  floatx4 acc[4][4];
#pragma unroll
  for (int mi = 0; mi < 4; ++mi)
#pragma unroll
    for (int ni = 0; ni < 4; ++ni) { acc[mi][ni][0] = 0.f; acc[mi][ni][1] = 0.f; acc[mi][ni][2] = 0.f; acc[mi][ni][3] = 0.f; }

  for (int kt = 0; kt < INNER; kt += 64) {
    __syncthreads();
    if (w < 2) {
#pragma unroll
      for (int ii = 0; ii < 16; ++ii)
        gll16(gsrc + (size_t)(bb1024 + srcrow[ii]) * INNER + kt + colsw, lp + ii * 512);
    } else {
#pragma unroll
      for (int ii = 0; ii < 16; ++ii)
        gll16(gsrc + (size_t)(c0 + ii * 8 + r8) * INNER + kt + colsw, lp + ii * 512);
    }
    __syncthreads();
#pragma unroll
    for (int ks2 = 0; ks2 < 2; ++ks2) {
      int pc = ((ks2 * 4 + q4) ^ sx7) << 3;
      short8 ah[4], al[4], bhf[4], blf[4];
#pragma unroll
      for (int mi = 0; mi < 4; ++mi) {
        int ra = (wr * 64 + mi * 16 + s) * 64 + pc;
        ah[mi] = *(const short8*)&Ah[ra];
        al[mi] = *(const short8*)&Al[ra];
      }
#pragma unroll
      for (int ni = 0; ni < 4; ++ni) {
        int rb = (wc * 64 + ni * 16 + s) * 64 + pc;
        bhf[ni] = *(const short8*)&Bh[rb];
        blf[ni] = *(const short8*)&Bl[rb];
      }
#pragma unroll
      for (int mi = 0; mi < 4; ++mi)
#pragma unroll
        for (int ni = 0; ni < 4; ++ni) {
          acc[mi][ni] = __builtin_amdgcn_mfma_f32_16x16x32_bf16(al[mi], bhf[ni], acc[mi][ni], 0, 0, 0);
          acc[mi][ni] = __builtin_amdgcn_mfma_f32_16x16x32_bf16(ah[mi], blf[ni], acc[mi][ni], 0, 0, 0);
          acc[mi][ni] = __builtin_amdgcn_mfma_f32_16x16x32_bf16(ah[mi], bhf[ni], acc[mi][ni], 0, 0, 0);
        }
    }
  }

#pragma unroll
  for (int ni = 0; ni < 4; ++ni) {
    int Cl = c0 + wc * 64 + ni * 16 + s;
    float bv = bias[Cl];
#pragma unroll
    for (int mi = 0; mi < 4; ++mi)
#pragma unroll
      for (int i = 0; i < 4; ++i) {
        int R = r0 + wr * 64 + mi * 16 + q4 * 4 + i;
        C[(size_t)R * DIM + Cl] = acc[mi][ni][i] + bv;
      }
  }
}

extern "C" void kernel_launch(void* const* d_in, const int* in_sizes, int n_in,
                              void* d_out, int out_size, void* d_ws, size_t ws_size,
                              hipStream_t stream) {
  const float* x      = (const float*)d_in[0];
  const int*   cpmask = (const int*)d_in[1];
  const float* w_qkv  = (const float*)d_in[2];
  const float* w_out  = (const float*)d_in[3];
  const float* b_out  = (const float*)d_in[4];
  const int*   pic    = (const int*)d_in[5];
  float* out = (float*)d_out;

  unsigned short* xhi   = (unsigned short*)d_ws;       // 8192*512 (reused as ohi after qkv)
  unsigned short* xlo   = xhi + 4194304;               // (reused as olo)
  unsigned short* wqhiT = xlo + 4194304;               // 1536*512
  unsigned short* wqloT = wqhiT + 786432;
  unsigned short* wohiT = wqloT + 786432;              // 512*512
  unsigned short* woloT = wohiT + 262144;
  unsigned short* qhi   = woloT + 262144;              // 64*1024*64 each
  unsigned short* qlo   = qhi + 4194304;
  unsigned short* khi   = qlo + 4194304;
  unsigned short* klo   = khi + 4194304;
  unsigned short* vbp   = klo + 4194304;               // (unused; layout stability)
  float* sph  = (float*)(vbp + 4194304);               // 64*1024
  float* sc   = sph + 65536;                           // (unused slot)
  float* nnzf = sc + 8192;                             // 1024
  int*   asc  = (int*)(nnzf + 1024);                   // 8*32
  int*   src  = asc + 512;                             // 8192
  unsigned long long* Mbits = (unsigned long long*)(src + 8192);  // 16*1024
  unsigned short* vTp = (unsigned short*)(Mbits + 16384);         // 64*64*1024

  unsigned short* ohi = xhi;   // alias: x planes dead after qkv_mfma
  unsigned short* olo = xlo;

  hipLaunchKernelGGL(nnz_kernel,    dim3(1024),    dim3(64),  0, stream, cpmask, nnzf, Mbits);
  hipLaunchKernelGGL(split_kernel,  dim3(4096),    dim3(256), 0, stream, x, xhi, xlo, 1048576);
  hipLaunchKernelGGL(tsplit_kernel, dim3(48, 16),  dim3(256), 0, stream, w_qkv, DIM, QKV_N, wqhiT, wqloT);
  hipLaunchKernelGGL(tsplit_kernel, dim3(16, 16),  dim3(256), 0, stream, w_out, INNER, DIM, wohiT, woloT);
  hipLaunchKernelGGL(qkv_mfma,      dim3(768),     dim3(256), 0, stream, xhi, xlo, wqhiT, wqloT,
                     qhi, qlo, khi, klo, vTp);
  hipLaunchKernelGGL(attn_kernel,   dim3(16, 64),  dim3(256), 0, stream, qhi, qlo, khi, klo, vTp,
                     Mbits, ohi, olo, sph);
  hipLaunchKernelGGL(score_select,  dim3(8),       dim3(256), 0, stream, sph, nnzf, pic, asc);
  hipLaunchKernelGGL(build_src,     dim3(8),       dim3(256), 0, stream, asc, pic, src);
  hipLaunchKernelGGL(out_mfma,      dim3(256),     dim3(256), 0, stream, ohi, olo, wohiT, woloT,
                     b_out, src, out);
}